// Round 2
// baseline (5052.767 us; speedup 1.0000x reference)
//
#include <hip/hip_runtime.h>
#include <math.h>

// ---------------------------------------------------------------------------
// HeteroDLSTM forward, fp32 baseline (r2: fast transcendentals + vec lstm_ew).
// Sizes (fixed): NS=20000 spots, NU=40000 users, E_us=200000, E_su=200000,
// E_ss=100000.
// ---------------------------------------------------------------------------

__device__ __forceinline__ float fsig(float x){ return 1.f/(1.f+__expf(-x)); }
__device__ __forceinline__ float ftanh(float x){ return 1.f - 2.f/(1.f+__expf(2.f*x)); }

// ---------------- generic 128x128 fp32 GEMM ----------------
// C[M,N] = [A1 | A2] @ B ; A1 [M,K1], A2 [M,K2] row-major; B [K1+K2,N] row-major.
// BT=1: B given as [N,K] row-major (C = A@B^T), requires K2==0.
// Requires: K1,K2 multiples of 16 (or K2==0), N multiple of 128.
template<int BT>
__global__ __launch_bounds__(256) void gemm_k(
    const float* __restrict__ A1, int K1,
    const float* __restrict__ A2, int K2,
    const float* __restrict__ Bg,
    float* __restrict__ C, int M, int N)
{
  const int K = K1 + K2;
  __shared__ float As[16][132];
  __shared__ float Bs[16][132];
  const int bm = blockIdx.x * 128;
  const int bn = blockIdx.y * 128;
  const int tid = threadIdx.x;
  const int tx = tid & 15, ty = tid >> 4;

  float acc[8][8];
#pragma unroll
  for (int i=0;i<8;i++)
#pragma unroll
    for (int j=0;j<8;j++) acc[i][j]=0.f;

  for (int k0 = 0; k0 < K; k0 += 16) {
    // A tile 128x16 (512 float4), store transposed into As
#pragma unroll
    for (int i=0;i<2;i++) {
      int f = tid + i*256;
      int ar = f >> 2, ac = (f & 3) << 2;
      int grow = bm + ar, kk = k0 + ac;
      float4 v = make_float4(0.f,0.f,0.f,0.f);
      if (grow < M) {
        if (kk < K1) v = *(const float4*)(A1 + (size_t)grow*K1 + kk);
        else         v = *(const float4*)(A2 + (size_t)grow*K2 + (kk-K1));
      }
      As[ac+0][ar]=v.x; As[ac+1][ar]=v.y; As[ac+2][ar]=v.z; As[ac+3][ar]=v.w;
    }
    // B tile 16x128
    if (BT == 0) {
#pragma unroll
      for (int i=0;i<2;i++) {
        int f = tid + i*256;
        int br = f >> 5, bc = (f & 31) << 2;
        float4 v = *(const float4*)(Bg + (size_t)(k0+br)*N + bn + bc);
        *(float4*)&Bs[br][bc] = v;
      }
    } else {
#pragma unroll
      for (int i=0;i<2;i++) {
        int f = tid + i*256;
        int nn = f >> 2, kc = (f & 3) << 2;
        float4 v = *(const float4*)(Bg + (size_t)(bn+nn)*K + k0 + kc);
        Bs[kc+0][nn]=v.x; Bs[kc+1][nn]=v.y; Bs[kc+2][nn]=v.z; Bs[kc+3][nn]=v.w;
      }
    }
    __syncthreads();
#pragma unroll
    for (int k=0;k<16;k++) {
      float a[8], b[8];
      *(float4*)&a[0] = *(float4*)&As[k][ty*4];
      *(float4*)&a[4] = *(float4*)&As[k][ty*4+64];
      *(float4*)&b[0] = *(float4*)&Bs[k][tx*4];
      *(float4*)&b[4] = *(float4*)&Bs[k][tx*4+64];
#pragma unroll
      for (int i=0;i<8;i++)
#pragma unroll
        for (int j=0;j<8;j++)
          acc[i][j] = fmaf(a[i], b[j], acc[i][j]);
    }
    __syncthreads();
  }
#pragma unroll
  for (int ih=0; ih<2; ih++)
#pragma unroll
    for (int i=0;i<4;i++) {
      int r = bm + ty*4 + i + ih*64;
      if (r < M) {
        float* Cr = C + (size_t)r*N + bn;
        *(float4*)(Cr + tx*4)      = *(float4*)&acc[ih*4+i][0];
        *(float4*)(Cr + tx*4 + 64) = *(float4*)&acc[ih*4+i][4];
      }
    }
}

// ---------------- attention pooling (after C1 = X@Wcat) ----------------
// C1: [ns*5, 512] chunk; out: [ns, 512]. 4 spots/block, 1 wave/spot.
__global__ __launch_bounds__(256) void att_pool(
    const float* __restrict__ C1, const float* __restrict__ q,
    float* __restrict__ outp, int ns)
{
  __shared__ float xh[20*512];
  int b0 = blockIdx.x * 4;
  int nrows = (ns - b0) * 5; if (nrows > 20) nrows = 20; if (nrows < 0) nrows = 0;
  for (int f = threadIdx.x; f < 2560; f += 256) {
    int row = f >> 7, c4 = (f & 127) << 2;
    float4 v = make_float4(0.f,0.f,0.f,0.f);
    if (row < nrows) v = *(const float4*)(C1 + (size_t)(b0*5+row)*512 + c4);
    *(float4*)&xh[row*512 + c4] = v;
  }
  __syncthreads();
  int wid = threadIdx.x >> 6, lane = threadIdx.x & 63;
  int n = b0 + wid;
  if (n >= ns) return;
  const float* X = &xh[wid*5*512];
  float att[4][5];
#pragma unroll
  for (int h=0; h<4; h++) {
#pragma unroll
    for (int s=0; s<5; s++) {
      float d = X[s*512 + h*128 + lane]      * q[h*128 + lane]
              + X[s*512 + h*128 + 64 + lane] * q[h*128 + 64 + lane];
#pragma unroll
      for (int off=32; off; off>>=1) d += __shfl_xor(d, off);
      att[h][s] = d > 0.f ? d : 0.2f*d;   // leaky_relu(.,0.2)
    }
    float m = att[h][0];
#pragma unroll
    for (int s=1;s<5;s++) m = fmaxf(m, att[h][s]);
    float sum = 0.f;
#pragma unroll
    for (int s=0;s<5;s++){ att[h][s] = __expf(att[h][s]-m); sum += att[h][s]; }
    float inv = 1.f/sum;
#pragma unroll
    for (int s=0;s<5;s++) att[h][s] *= inv;
  }
  int c0 = lane * 8;
  int h = c0 >> 7;
  float o[8] = {0,0,0,0,0,0,0,0};
#pragma unroll
  for (int s=0;s<5;s++) {
    float w = att[h][s];
    const float* Xr = X + s*512 + c0;
#pragma unroll
    for (int j=0;j<8;j++) o[j] = fmaf(w, Xr[j], o[j]);
  }
  float* op = outp + (size_t)n*512 + c0;
  *(float4*)op     = *(float4*)&o[0];
  *(float4*)(op+4) = *(float4*)&o[4];
}

// ---------------- CSR build ----------------
__global__ void fillz(int* __restrict__ p, int n){
  int i = blockIdx.x*256 + threadIdx.x; if (i < n) p[i] = 0;
}
__global__ void hist_k(const int* __restrict__ dst, int* __restrict__ cnt, int E){
  int e = blockIdx.x*256 + threadIdx.x; if (e < E) atomicAdd(&cnt[dst[e]], 1);
}
__global__ void scan_k(int* __restrict__ cnt, int* __restrict__ offs, int n){
  __shared__ int sm[1024];
  int tid = threadIdx.x;
  int running = 0;
  for (int base = 0; base < n; base += 1024) {
    int i = base + tid;
    int v = (i < n) ? cnt[i] : 0;
    sm[tid] = v;
    __syncthreads();
    for (int off=1; off<1024; off<<=1) {
      int add = (tid >= off) ? sm[tid-off] : 0;
      __syncthreads();
      sm[tid] += add;
      __syncthreads();
    }
    int incl = sm[tid];
    int tot  = sm[1023];
    int excl = running + incl - v;
    if (i < n) { offs[i] = excl; cnt[i] = excl; }
    running += tot;
    __syncthreads();
  }
  if (tid == 0) offs[n] = running;
}
__global__ void place_k(const int* __restrict__ src, const int* __restrict__ dst,
                        int* __restrict__ cur, int* __restrict__ srt, int E){
  int e = blockIdx.x*256 + threadIdx.x;
  if (e < E) { int p = atomicAdd(&cur[dst[e]], 1); srt[p] = src[e]; }
}

// ---------------- segment max (PyG MaxAggregation: empty -> 0) ----------------
__global__ __launch_bounds__(256) void seg_max(
    const float* __restrict__ S, const int* __restrict__ offs,
    const int* __restrict__ ssrc, float* __restrict__ agg, int Nt)
{
  int t = blockIdx.x*4 + (threadIdx.x >> 6);
  if (t >= Nt) return;
  int lane = threadIdx.x & 63;
  int e0 = offs[t], e1 = offs[t+1];
  float4 m = make_float4(-INFINITY,-INFINITY,-INFINITY,-INFINITY);
  for (int e = e0; e < e1; e++) {
    int s = ssrc[e];
    float4 v = *(const float4*)(S + (size_t)s*256 + lane*4);
    m.x = fmaxf(m.x,v.x); m.y = fmaxf(m.y,v.y); m.z = fmaxf(m.z,v.z); m.w = fmaxf(m.w,v.w);
  }
  if (e1 == e0) m = make_float4(0.f,0.f,0.f,0.f);
  *(float4*)(agg + (size_t)t*256 + lane*4) = m;
}

// ---------------- misc elementwise ----------------
__global__ void avg2(const float* __restrict__ a, const float* __restrict__ b,
                     float* __restrict__ o, int n4){
  int i = blockIdx.x*256 + threadIdx.x;
  if (i < n4) {
    float4 x = ((const float4*)a)[i], y = ((const float4*)b)[i];
    float4 r; r.x=(x.x+y.x)*0.5f; r.y=(x.y+y.y)*0.5f; r.z=(x.z+y.z)*0.5f; r.w=(x.w+y.w)*0.5f;
    ((float4*)o)[i] = r;
  }
}

// LSTM gates from pre-GEMM g [rows,1024]; gate order i,f,g,o.
// 64-lane group per row, float4 per thread (j = lane*4 .. lane*4+3).
// mode 0: out=h ; mode 1: out=relu(h) ; mode 2: out=relu((out+h)*0.5)
__global__ __launch_bounds__(256) void lstm_ew(
    const float* __restrict__ g, const float* __restrict__ b,
    const float* __restrict__ c_in, float* __restrict__ outp,
    int rows, int r0, int mode)
{
  int n = blockIdx.x*4 + (threadIdx.x >> 6);
  if (n >= rows) return;
  int j = (threadIdx.x & 63) * 4;
  const float* gr = g + (size_t)n*1024;
  float4 ig = *(const float4*)(gr + j);
  float4 fg = *(const float4*)(gr + 256 + j);
  float4 gg = *(const float4*)(gr + 512 + j);
  float4 og = *(const float4*)(gr + 768 + j);
  float4 bi = *(const float4*)(b + j);
  float4 bf = *(const float4*)(b + 256 + j);
  float4 bg = *(const float4*)(b + 512 + j);
  float4 bo = *(const float4*)(b + 768 + j);
  float4 c  = *(const float4*)(c_in + (size_t)(r0+n)*256 + j);
  float h[4];
  {
    float c2;
    c2 = fsig(fg.x+bf.x)*c.x + fsig(ig.x+bi.x)*ftanh(gg.x+bg.x); h[0] = fsig(og.x+bo.x)*ftanh(c2);
    c2 = fsig(fg.y+bf.y)*c.y + fsig(ig.y+bi.y)*ftanh(gg.y+bg.y); h[1] = fsig(og.y+bo.y)*ftanh(c2);
    c2 = fsig(fg.z+bf.z)*c.z + fsig(ig.z+bi.z)*ftanh(gg.z+bg.z); h[2] = fsig(og.z+bo.z)*ftanh(c2);
    c2 = fsig(fg.w+bf.w)*c.w + fsig(ig.w+bi.w)*ftanh(gg.w+bg.w); h[3] = fsig(og.w+bo.w)*ftanh(c2);
  }
  float* o = outp + (size_t)(r0+n)*256 + j;
  if (mode == 0) {
    *(float4*)o = make_float4(h[0],h[1],h[2],h[3]);
  } else if (mode == 1) {
    *(float4*)o = make_float4(fmaxf(h[0],0.f),fmaxf(h[1],0.f),fmaxf(h[2],0.f),fmaxf(h[3],0.f));
  } else {
    float4 p = *(const float4*)o;
    *(float4*)o = make_float4(fmaxf((p.x+h[0])*0.5f,0.f), fmaxf((p.y+h[1])*0.5f,0.f),
                              fmaxf((p.z+h[2])*0.5f,0.f), fmaxf((p.w+h[3])*0.5f,0.f));
  }
}

__global__ __launch_bounds__(256) void matvec(const float* __restrict__ X,
    const float* __restrict__ w, const float* __restrict__ bias,
    float* __restrict__ o, int N){
  int r = blockIdx.x*4 + (threadIdx.x >> 6);
  if (r >= N) return;
  int lane = threadIdx.x & 63;
  float4 x  = *(const float4*)(X + (size_t)r*256 + lane*4);
  float4 ww = *(const float4*)(w + lane*4);
  float d = x.x*ww.x + x.y*ww.y + x.z*ww.z + x.w*ww.w;
#pragma unroll
  for (int off=32; off; off>>=1) d += __shfl_xor(d, off);
  if (lane == 0) o[r] = d + bias[0];
}

// att_W [4,512,128] -> Wcat [512, 512] with Wcat[d][h*128+k] = att_W[h][d][k]
__global__ void repack_attw(const float* __restrict__ W, float* __restrict__ o){
  int idx = blockIdx.x*256 + threadIdx.x;
  if (idx >= 4*512*128) return;
  int h = idx >> 16, rem = idx & 65535;
  int d = rem >> 7, k = rem & 127;
  o[(size_t)d*512 + h*128 + k] = W[idx];
}

// Whh [1024,256] -> out [256,1024]
__global__ void transpose_wh(const float* __restrict__ in, float* __restrict__ out){
  __shared__ float t[32][33];
  int rb = blockIdx.x*32, cb = blockIdx.y*32;
  int tx = threadIdx.x, ty = threadIdx.y;
  for (int i=0;i<32;i+=8) t[ty+i][tx] = in[(size_t)(rb+ty+i)*256 + cb+tx];
  __syncthreads();
  for (int i=0;i<32;i+=8) out[(size_t)(cb+ty+i)*1024 + rb+tx] = t[tx][ty+i];
}

// ---------------------------------------------------------------------------
extern "C" void kernel_launch(void* const* d_in, const int* in_sizes, int n_in,
                              void* d_out, int out_size, void* d_ws, size_t ws_size,
                              hipStream_t stream)
{
  const float* x_spot = (const float*)d_in[0];
  const float* x_user = (const float*)d_in[1];
  const float* attW   = (const float*)d_in[2];
  const float* attq   = (const float*)d_in[3];
  const float* Wsrc0[3] = { (const float*)d_in[4], (const float*)d_in[5], (const float*)d_in[6] };
  const float* Wtgt0[3] = { (const float*)d_in[7], (const float*)d_in[8], (const float*)d_in[9] };
  const float* Wih0 = (const float*)d_in[10];
  const float* Whh0 = (const float*)d_in[11];
  const float* b0   = (const float*)d_in[12];
  const float* Wsrc1 = (const float*)d_in[13];
  const float* Wtgt1 = (const float*)d_in[14];
  const float* Wih1 = (const float*)d_in[15];
  const float* Whh1 = (const float*)d_in[16];
  const float* b1   = (const float*)d_in[17];
  const float* linSW = (const float*)d_in[18];
  const float* linSb = (const float*)d_in[19];
  const float* linUW = (const float*)d_in[20];
  const float* linUb = (const float*)d_in[21];
  const int* src_us = (const int*)d_in[22];
  const int* dst_us = (const int*)d_in[23];
  const int* src_su = (const int*)d_in[24];
  const int* dst_su = (const int*)d_in[25];
  const int* src_ss = (const int*)d_in[26];
  const int* dst_ss = (const int*)d_in[27];
  float* out = (float*)d_out;
  float* ws  = (float*)d_ws;
  int*   wsi = (int*)d_ws;

  // ---- workspace layout (float offsets); total ~356 MB ----
  const size_t WCAT = 0;              // 512*512
  const size_t BC00 = 262144;         // [768,1024]
  const size_t BC01 = 1048576;        // [512,1024]
  const size_t BC02 = 1572864;        // [768,1024]
  const size_t BC10 = 2359296;        // [512,1024]
  const size_t BC11 = 2883584;
  const size_t BC12 = 3407872;
  const size_t X0S  = 3932160;        // [20000,512]
  const size_t SCR  = 14172160;       // 12.8M floats scratch (C1 chunk / src_out / g chunk)
  const size_t AGG0 = 26972160;       // [20000,256]
  const size_t AGG1 = 32092160;       // [40000,256]
  const size_t AGG2 = 42332160;       // [20000,256]
  const size_t METAS= 47452160;       // [20000,256]
  const size_t X1S  = 52572160;       // [20000,256]
  const size_t X1U  = 57692160;       // [40000,256]
  const size_t X2S  = 67932160;
  const size_t X2U  = 78172160;
  const size_t IB   = 88412160;       // int area base (int offsets below rel. to IB)
  const int OF_US = 0,      CU_US = 20001,  SR_US = 40001;
  const int OF_SU = 240001, CU_SU = 280002, SR_SU = 320002;
  const int OF_SS = 520002, CU_SS = 540003, SR_SS = 560003;

  // ---- phase 0: weight prep ----
  repack_attw<<<1024,256,0,stream>>>(attW, ws+WCAT);
  struct { const float* Wt; int Kt; const float* Wi; const float* Wh; size_t bc; } cfg[6] = {
    { Wtgt0[0], 512, Wih0,        Whh0,        BC00 },
    { Wtgt0[1], 256, Wih0+262144, Whh0+262144, BC01 },
    { Wtgt0[2], 512, Wih0+524288, Whh0+524288, BC02 },
    { Wtgt1,        256, Wih1,        Whh1,        BC10 },
    { Wtgt1+65536,  256, Wih1+262144, Whh1+262144, BC11 },
    { Wtgt1+131072, 256, Wih1+524288, Whh1+524288, BC12 },
  };
  for (int i=0;i<6;i++){
    dim3 g((cfg[i].Kt+127)/128, 8);
    gemm_k<1><<<g,256,0,stream>>>(cfg[i].Wt, 256, cfg[i].Wt, 0, cfg[i].Wi,
                                  ws+cfg[i].bc, cfg[i].Kt, 1024);
    transpose_wh<<<dim3(32,8),dim3(32,8),0,stream>>>(cfg[i].Wh,
                                  ws+cfg[i].bc + (size_t)cfg[i].Kt*1024);
  }

  // ---- phase 1: attention pooling -> X0S [20000,512] (4 chunks of 5000 spots) ----
  for (int c=0;c<4;c++){
    gemm_k<0><<<dim3(196,4),256,0,stream>>>(x_spot + (size_t)c*12800000, 512,
                                            x_spot, 0, ws+WCAT, ws+SCR, 25000, 512);
    att_pool<<<1250,256,0,stream>>>(ws+SCR, attq, ws+X0S + (size_t)c*2560000, 5000);
  }

  // ---- phase 2: CSR for 3 edge types (shared across both layers) ----
  struct { const int* src; const int* dst; int E; int Nt; int of, cu, sr; } et[3] = {
    { src_us, dst_us, 200000, 20000, OF_US, CU_US, SR_US },
    { src_su, dst_su, 200000, 40000, OF_SU, CU_SU, SR_SU },
    { src_ss, dst_ss, 100000, 20000, OF_SS, CU_SS, SR_SS },
  };
  for (int i=0;i<3;i++){
    fillz<<<(et[i].Nt+255)/256,256,0,stream>>>(wsi+IB+et[i].cu, et[i].Nt);
    hist_k<<<(et[i].E+255)/256,256,0,stream>>>(et[i].dst, wsi+IB+et[i].cu, et[i].E);
    scan_k<<<1,1024,0,stream>>>(wsi+IB+et[i].cu, wsi+IB+et[i].of, et[i].Nt);
    place_k<<<(et[i].E+255)/256,256,0,stream>>>(et[i].src, et[i].dst,
                                                wsi+IB+et[i].cu, wsi+IB+et[i].sr, et[i].E);
  }

  // ---- layers ----
  for (int L=0; L<2; L++){
    const float* xs = (L==0) ? ws+X0S : ws+X1S;   // spot features
    const float* xu = (L==0) ? x_user : ws+X1U;   // user features
    int Ks = (L==0) ? 512 : 256;                  // spot feature dim
    const float* Wsrc_e[3];
    if (L==0){ Wsrc_e[0]=Wsrc0[0]; Wsrc_e[1]=Wsrc0[1]; Wsrc_e[2]=Wsrc0[2]; }
    else     { Wsrc_e[0]=Wsrc1; Wsrc_e[1]=Wsrc1+65536; Wsrc_e[2]=Wsrc1+131072; }
    int Ksrc_e[3] = { 256, Ks, Ks };              // source dims: user, spot, spot
    size_t BC_e[3] = { (L==0)?BC00:BC10, (L==0)?BC01:BC11, (L==0)?BC02:BC12 };
    int Kt_e[3] = { Ks, 256, Ks };                // target dims: spot, user, spot
    const float* bb = (L==0) ? b0 : b1;
    float* outS = (L==0) ? ws+X1S : ws+X2S;
    float* outU = (L==0) ? ws+X1U : ws+X2U;

    // src GEMMs + scatter-max
    // e0: user -> spot
    gemm_k<0><<<dim3(313,2),256,0,stream>>>(xu, 256, xu, 0, Wsrc_e[0], ws+SCR, 40000, 256);
    seg_max<<<5000,256,0,stream>>>(ws+SCR, wsi+IB+OF_US, wsi+IB+SR_US, ws+AGG0, 20000);
    // e1: spot -> user
    gemm_k<0><<<dim3(157,2),256,0,stream>>>(xs, Ksrc_e[1], xs, 0, Wsrc_e[1], ws+SCR, 20000, 256);
    seg_max<<<10000,256,0,stream>>>(ws+SCR, wsi+IB+OF_SU, wsi+IB+SR_SU, ws+AGG1, 40000);
    // e2: spot -> spot
    gemm_k<0><<<dim3(157,2),256,0,stream>>>(xs, Ksrc_e[2], xs, 0, Wsrc_e[2], ws+SCR, 20000, 256);
    seg_max<<<5000,256,0,stream>>>(ws+SCR, wsi+IB+OF_SS, wsi+IB+SR_SS, ws+AGG2, 20000);
    // meta_spot = (agg0+agg2)/2 ; meta_user = agg1
    avg2<<<5000,256,0,stream>>>(ws+AGG0, ws+AGG2, ws+METAS, 1280000);

    // LSTM per edge type: g = [x_t | agg] @ B_cat, then gates (chunks of 10000 rows)
    // e0 -> spot (mode 0: write h)
    for (int ch=0; ch<2; ch++){
      gemm_k<0><<<dim3(79,8),256,0,stream>>>(xs + (size_t)ch*10000*Kt_e[0], Kt_e[0],
            ws+AGG0 + (size_t)ch*10000*256, 256, ws+BC_e[0], ws+SCR, 10000, 1024);
      lstm_ew<<<2500,256,0,stream>>>(ws+SCR, bb+0, ws+METAS, outS, 10000, ch*10000, 0);
    }
    // e1 -> user (mode 1: relu(h))
    for (int ch=0; ch<4; ch++){
      gemm_k<0><<<dim3(79,8),256,0,stream>>>(xu + (size_t)ch*10000*256, 256,
            ws+AGG1 + (size_t)ch*10000*256, 256, ws+BC_e[1], ws+SCR, 10000, 1024);
      lstm_ew<<<2500,256,0,stream>>>(ws+SCR, bb+1024, ws+AGG1, outU, 10000, ch*10000, 1);
    }
    // e2 -> spot (mode 2: relu((prev+h)/2))
    for (int ch=0; ch<2; ch++){
      gemm_k<0><<<dim3(79,8),256,0,stream>>>(xs + (size_t)ch*10000*Kt_e[2], Kt_e[2],
            ws+AGG2 + (size_t)ch*10000*256, 256, ws+BC_e[2], ws+SCR, 10000, 1024);
      lstm_ew<<<2500,256,0,stream>>>(ws+SCR, bb+2048, ws+METAS, outS, 10000, ch*10000, 2);
    }
  }

  // ---- outputs ----
  avg2<<<5000,256,0,stream>>>(ws+X1S, ws+X2S, out, 1280000);
  avg2<<<10000,256,0,stream>>>(ws+X1U, ws+X2U, out+5120000, 2560000);
  matvec<<<5000,256,0,stream>>>(ws+X2S, linSW, linSb, out+15360000, 20000);
  matvec<<<10000,256,0,stream>>>(ws+X2U, linUW, linUb, out+15380000, 40000);

  (void)in_sizes; (void)n_in; (void)out_size; (void)ws_size;
}

// Round 3
// 3062.888 us; speedup vs baseline: 1.6497x; 1.6497x over previous
//
#include <hip/hip_runtime.h>
#include <math.h>

// ---------------------------------------------------------------------------
// HeteroDLSTM forward. r3: bf16x2 (split-float) MFMA GEMMs.
// NS=20000 spots, NU=40000 users, E_us=200000, E_su=200000, E_ss=100000.
// ---------------------------------------------------------------------------

typedef unsigned short u16;
typedef short short8 __attribute__((ext_vector_type(8)));
typedef float f32x4 __attribute__((ext_vector_type(4)));

__device__ __forceinline__ float fsig(float x){ return 1.f/(1.f+__expf(-x)); }
__device__ __forceinline__ float ftanh(float x){ return 1.f - 2.f/(1.f+__expf(2.f*x)); }
__device__ __forceinline__ u16 bf16rne(float x){
  unsigned u = __float_as_uint(x);
  unsigned r = (u + 0x7FFFu + ((u>>16)&1u)) >> 16;
  return (u16)r;
}

// ---------------- fp32 GEMM (weight prep only) ----------------
// C = A @ B^T ; A [M,K] row-major, B [N,K] row-major. K mult of 16, N mult of 128.
__global__ __launch_bounds__(256) void gemm_wt(
    const float* __restrict__ A1, int K,
    const float* __restrict__ Bg,
    float* __restrict__ C, int M, int N)
{
  __shared__ float As[16][132];
  __shared__ float Bs[16][132];
  const int bm = blockIdx.x * 128;
  const int bn = blockIdx.y * 128;
  const int tid = threadIdx.x;
  const int tx = tid & 15, ty = tid >> 4;

  float acc[8][8];
#pragma unroll
  for (int i=0;i<8;i++)
#pragma unroll
    for (int j=0;j<8;j++) acc[i][j]=0.f;

  for (int k0 = 0; k0 < K; k0 += 16) {
#pragma unroll
    for (int i=0;i<2;i++) {
      int f = tid + i*256;
      int ar = f >> 2, ac = (f & 3) << 2;
      int grow = bm + ar, kk = k0 + ac;
      float4 v = make_float4(0.f,0.f,0.f,0.f);
      if (grow < M) v = *(const float4*)(A1 + (size_t)grow*K + kk);
      As[ac+0][ar]=v.x; As[ac+1][ar]=v.y; As[ac+2][ar]=v.z; As[ac+3][ar]=v.w;
    }
#pragma unroll
    for (int i=0;i<2;i++) {
      int f = tid + i*256;
      int nn = f >> 2, kc = (f & 3) << 2;
      float4 v = *(const float4*)(Bg + (size_t)(bn+nn)*K + k0 + kc);
      Bs[kc+0][nn]=v.x; Bs[kc+1][nn]=v.y; Bs[kc+2][nn]=v.z; Bs[kc+3][nn]=v.w;
    }
    __syncthreads();
#pragma unroll
    for (int k=0;k<16;k++) {
      float a[8], b[8];
      *(float4*)&a[0] = *(float4*)&As[k][ty*4];
      *(float4*)&a[4] = *(float4*)&As[k][ty*4+64];
      *(float4*)&b[0] = *(float4*)&Bs[k][tx*4];
      *(float4*)&b[4] = *(float4*)&Bs[k][tx*4+64];
#pragma unroll
      for (int i=0;i<8;i++)
#pragma unroll
        for (int j=0;j<8;j++)
          acc[i][j] = fmaf(a[i], b[j], acc[i][j]);
    }
    __syncthreads();
  }
#pragma unroll
  for (int ih=0; ih<2; ih++)
#pragma unroll
    for (int i=0;i<4;i++) {
      int r = bm + ty*4 + i + ih*64;
      if (r < M) {
        float* Cr = C + (size_t)r*N + bn;
        *(float4*)(Cr + tx*4)      = *(float4*)&acc[ih*4+i][0];
        *(float4*)(Cr + tx*4 + 64) = *(float4*)&acc[ih*4+i][4];
      }
    }
}

// ---------------- B pre-convert: fp32 [K][N] -> bf16 hi/lo planes [N][K] ----
__global__ void btrans(const float* __restrict__ in, int K, int N,
                       u16* __restrict__ oh, u16* __restrict__ ol){
  __shared__ float t[32][33];
  int k0 = blockIdx.x*32, n0 = blockIdx.y*32;
  int tx = threadIdx.x, ty = threadIdx.y;
  for (int r=0;r<32;r+=8) t[ty+r][tx] = in[(size_t)(k0+ty+r)*N + n0+tx];
  __syncthreads();
  for (int r=0;r<32;r+=8){
    int n = n0+ty+r, k = k0+tx;
    float x = t[tx][ty+r];
    u16 h = bf16rne(x);
    oh[(size_t)n*K + k] = h;
    ol[(size_t)n*K + k] = bf16rne(x - __uint_as_float(((unsigned)h)<<16));
  }
}

// ---------------- bf16x2 MFMA GEMM ----------------
// C[M,N] = [A1 | A2] @ B ; A fp32 row-major; B pre-converted bf16 hi/lo [N][K].
// 128x128 tile, BK=32, 4 waves (2x2), each wave 64x64 via 4x4 16x16x32 MFMA.
// Requires: K1,K2 mult of 8 (K2 may be 0), K mult of 32, N mult of 128.
__global__ __launch_bounds__(256,2) void gemm_mfma(
    const float* __restrict__ A1, int K1,
    const float* __restrict__ A2, int K2,
    const u16* __restrict__ Bh, const u16* __restrict__ Bl,
    float* __restrict__ C, int M, int N)
{
  const int K = K1 + K2;
  __shared__ u16 As[2][128*40];   // [plane][m*40 + k], rows padded to 40 (80B)
  __shared__ u16 Bs[2][128*40];   // [plane][n*40 + k]
  const int tid = threadIdx.x;
  const int bm = blockIdx.x * 128, bn = blockIdx.y * 128;
  const int w = tid >> 6, l = tid & 63;
  const int wr = w >> 1, wc = w & 1;
  const int lm = l & 15, lk = l >> 4;
  const int sm = tid & 127;        // staging row (A) / col (B)
  const int sko0 = tid >> 7;       // staging k-octet base

  f32x4 acc[4][4];
#pragma unroll
  for (int i=0;i<4;i++)
#pragma unroll
    for (int j=0;j<4;j++) acc[i][j] = (f32x4){0.f,0.f,0.f,0.f};

  for (int k0 = 0; k0 < K; k0 += 32) {
#pragma unroll
    for (int p = 0; p < 2; p++) {
      const int ko = sko0 + p*2;
      const int off = sm*40 + ko*8;
      // ---- stage A (fp32 -> hi/lo bf16) ----
      {
        int row = bm + sm;
        int kk = k0 + ko*8;
        float xv[8];
        if (row < M) {
          const float* src; int kloc;
          if (kk < K1) { src = A1 + (size_t)row*K1; kloc = kk; }
          else         { src = A2 + (size_t)row*K2; kloc = kk - K1; }
          float4 v0 = *(const float4*)(src + kloc);
          float4 v1 = *(const float4*)(src + kloc + 4);
          xv[0]=v0.x; xv[1]=v0.y; xv[2]=v0.z; xv[3]=v0.w;
          xv[4]=v1.x; xv[5]=v1.y; xv[6]=v1.z; xv[7]=v1.w;
        } else {
#pragma unroll
          for (int j=0;j<8;j++) xv[j]=0.f;
        }
        short8 hv, lv;
#pragma unroll
        for (int j=0;j<8;j++){
          u16 h = bf16rne(xv[j]);
          hv[j] = (short)h;
          lv[j] = (short)bf16rne(xv[j] - __uint_as_float(((unsigned)h)<<16));
        }
        *(short8*)&As[0][off] = hv;
        *(short8*)&As[1][off] = lv;
      }
      // ---- stage B (bf16 copy) ----
      {
        const size_t bgo = (size_t)(bn + sm)*K + k0 + ko*8;
        *(short8*)&Bs[0][off] = *(const short8*)(Bh + bgo);
        *(short8*)&Bs[1][off] = *(const short8*)(Bl + bgo);
      }
    }
    __syncthreads();
    short8 ah[4], al[4], bh[4], bl[4];
#pragma unroll
    for (int i=0;i<4;i++){
      int ao = (wr*64 + i*16 + lm)*40 + lk*8;
      ah[i] = *(short8*)&As[0][ao];
      al[i] = *(short8*)&As[1][ao];
      int bo = (wc*64 + i*16 + lm)*40 + lk*8;
      bh[i] = *(short8*)&Bs[0][bo];
      bl[i] = *(short8*)&Bs[1][bo];
    }
#pragma unroll
    for (int i=0;i<4;i++)
#pragma unroll
      for (int j=0;j<4;j++){
        acc[i][j] = __builtin_amdgcn_mfma_f32_16x16x32_bf16(ah[i], bh[j], acc[i][j], 0,0,0);
        acc[i][j] = __builtin_amdgcn_mfma_f32_16x16x32_bf16(ah[i], bl[j], acc[i][j], 0,0,0);
        acc[i][j] = __builtin_amdgcn_mfma_f32_16x16x32_bf16(al[i], bh[j], acc[i][j], 0,0,0);
      }
    __syncthreads();
  }
  // ---- epilogue: C/D layout col=lane&15, row=(lane>>4)*4+reg ----
#pragma unroll
  for (int i=0;i<4;i++){
    int row0 = bm + wr*64 + i*16 + lk*4;
#pragma unroll
    for (int r=0;r<4;r++){
      int row = row0 + r;
      if (row < M){
        float* Cr = C + (size_t)row*N + bn + wc*64 + lm;
#pragma unroll
        for (int j=0;j<4;j++) Cr[j*16] = acc[i][j][r];
      }
    }
  }
}

// ---------------- attention pooling (after C1 = X@Wcat) ----------------
__global__ __launch_bounds__(256) void att_pool(
    const float* __restrict__ C1, const float* __restrict__ q,
    float* __restrict__ outp, int ns)
{
  __shared__ float xh[20*512];
  int b0 = blockIdx.x * 4;
  int nrows = (ns - b0) * 5; if (nrows > 20) nrows = 20; if (nrows < 0) nrows = 0;
  for (int f = threadIdx.x; f < 2560; f += 256) {
    int row = f >> 7, c4 = (f & 127) << 2;
    float4 v = make_float4(0.f,0.f,0.f,0.f);
    if (row < nrows) v = *(const float4*)(C1 + (size_t)(b0*5+row)*512 + c4);
    *(float4*)&xh[row*512 + c4] = v;
  }
  __syncthreads();
  int wid = threadIdx.x >> 6, lane = threadIdx.x & 63;
  int n = b0 + wid;
  if (n >= ns) return;
  const float* X = &xh[wid*5*512];
  float att[4][5];
#pragma unroll
  for (int h=0; h<4; h++) {
#pragma unroll
    for (int s=0; s<5; s++) {
      float d = X[s*512 + h*128 + lane]      * q[h*128 + lane]
              + X[s*512 + h*128 + 64 + lane] * q[h*128 + 64 + lane];
#pragma unroll
      for (int off=32; off; off>>=1) d += __shfl_xor(d, off);
      att[h][s] = d > 0.f ? d : 0.2f*d;
    }
    float m = att[h][0];
#pragma unroll
    for (int s=1;s<5;s++) m = fmaxf(m, att[h][s]);
    float sum = 0.f;
#pragma unroll
    for (int s=0;s<5;s++){ att[h][s] = __expf(att[h][s]-m); sum += att[h][s]; }
    float inv = 1.f/sum;
#pragma unroll
    for (int s=0;s<5;s++) att[h][s] *= inv;
  }
  int c0 = lane * 8;
  int h = c0 >> 7;
  float o[8] = {0,0,0,0,0,0,0,0};
#pragma unroll
  for (int s=0;s<5;s++) {
    float w = att[h][s];
    const float* Xr = X + s*512 + c0;
#pragma unroll
    for (int j=0;j<8;j++) o[j] = fmaf(w, Xr[j], o[j]);
  }
  float* op = outp + (size_t)n*512 + c0;
  *(float4*)op     = *(float4*)&o[0];
  *(float4*)(op+4) = *(float4*)&o[4];
}

// ---------------- CSR build ----------------
__global__ void fillz(int* __restrict__ p, int n){
  int i = blockIdx.x*256 + threadIdx.x; if (i < n) p[i] = 0;
}
__global__ void hist_k(const int* __restrict__ dst, int* __restrict__ cnt, int E){
  int e = blockIdx.x*256 + threadIdx.x; if (e < E) atomicAdd(&cnt[dst[e]], 1);
}
__global__ void scan_k(int* __restrict__ cnt, int* __restrict__ offs, int n){
  __shared__ int sm[1024];
  int tid = threadIdx.x;
  int running = 0;
  for (int base = 0; base < n; base += 1024) {
    int i = base + tid;
    int v = (i < n) ? cnt[i] : 0;
    sm[tid] = v;
    __syncthreads();
    for (int off=1; off<1024; off<<=1) {
      int add = (tid >= off) ? sm[tid-off] : 0;
      __syncthreads();
      sm[tid] += add;
      __syncthreads();
    }
    int incl = sm[tid];
    int tot  = sm[1023];
    int excl = running + incl - v;
    if (i < n) { offs[i] = excl; cnt[i] = excl; }
    running += tot;
    __syncthreads();
  }
  if (tid == 0) offs[n] = running;
}
__global__ void place_k(const int* __restrict__ src, const int* __restrict__ dst,
                        int* __restrict__ cur, int* __restrict__ srt, int E){
  int e = blockIdx.x*256 + threadIdx.x;
  if (e < E) { int p = atomicAdd(&cur[dst[e]], 1); srt[p] = src[e]; }
}

// ---------------- segment max (empty -> 0) ----------------
__global__ __launch_bounds__(256) void seg_max(
    const float* __restrict__ S, const int* __restrict__ offs,
    const int* __restrict__ ssrc, float* __restrict__ agg, int Nt)
{
  int t = blockIdx.x*4 + (threadIdx.x >> 6);
  if (t >= Nt) return;
  int lane = threadIdx.x & 63;
  int e0 = offs[t], e1 = offs[t+1];
  float4 m = make_float4(-INFINITY,-INFINITY,-INFINITY,-INFINITY);
  for (int e = e0; e < e1; e++) {
    int s = ssrc[e];
    float4 v = *(const float4*)(S + (size_t)s*256 + lane*4);
    m.x = fmaxf(m.x,v.x); m.y = fmaxf(m.y,v.y); m.z = fmaxf(m.z,v.z); m.w = fmaxf(m.w,v.w);
  }
  if (e1 == e0) m = make_float4(0.f,0.f,0.f,0.f);
  *(float4*)(agg + (size_t)t*256 + lane*4) = m;
}

// ---------------- misc elementwise ----------------
__global__ void avg2(const float* __restrict__ a, const float* __restrict__ b,
                     float* __restrict__ o, int n4){
  int i = blockIdx.x*256 + threadIdx.x;
  if (i < n4) {
    float4 x = ((const float4*)a)[i], y = ((const float4*)b)[i];
    float4 r; r.x=(x.x+y.x)*0.5f; r.y=(x.y+y.y)*0.5f; r.z=(x.z+y.z)*0.5f; r.w=(x.w+y.w)*0.5f;
    ((float4*)o)[i] = r;
  }
}

// LSTM gates; 64-lane group per row, float4 per thread.
// mode 0: out=h ; mode 1: out=relu(h) ; mode 2: out=relu((out+h)*0.5)
__global__ __launch_bounds__(256) void lstm_ew(
    const float* __restrict__ g, const float* __restrict__ b,
    const float* __restrict__ c_in, float* __restrict__ outp,
    int rows, int r0, int mode)
{
  int n = blockIdx.x*4 + (threadIdx.x >> 6);
  if (n >= rows) return;
  int j = (threadIdx.x & 63) * 4;
  const float* gr = g + (size_t)n*1024;
  float4 ig = *(const float4*)(gr + j);
  float4 fg = *(const float4*)(gr + 256 + j);
  float4 gg = *(const float4*)(gr + 512 + j);
  float4 og = *(const float4*)(gr + 768 + j);
  float4 bi = *(const float4*)(b + j);
  float4 bf = *(const float4*)(b + 256 + j);
  float4 bg = *(const float4*)(b + 512 + j);
  float4 bo = *(const float4*)(b + 768 + j);
  float4 c  = *(const float4*)(c_in + (size_t)(r0+n)*256 + j);
  float h[4];
  {
    float c2;
    c2 = fsig(fg.x+bf.x)*c.x + fsig(ig.x+bi.x)*ftanh(gg.x+bg.x); h[0] = fsig(og.x+bo.x)*ftanh(c2);
    c2 = fsig(fg.y+bf.y)*c.y + fsig(ig.y+bi.y)*ftanh(gg.y+bg.y); h[1] = fsig(og.y+bo.y)*ftanh(c2);
    c2 = fsig(fg.z+bf.z)*c.z + fsig(ig.z+bi.z)*ftanh(gg.z+bg.z); h[2] = fsig(og.z+bo.z)*ftanh(c2);
    c2 = fsig(fg.w+bf.w)*c.w + fsig(ig.w+bi.w)*ftanh(gg.w+bg.w); h[3] = fsig(og.w+bo.w)*ftanh(c2);
  }
  float* o = outp + (size_t)(r0+n)*256 + j;
  if (mode == 0) {
    *(float4*)o = make_float4(h[0],h[1],h[2],h[3]);
  } else if (mode == 1) {
    *(float4*)o = make_float4(fmaxf(h[0],0.f),fmaxf(h[1],0.f),fmaxf(h[2],0.f),fmaxf(h[3],0.f));
  } else {
    float4 p = *(const float4*)o;
    *(float4*)o = make_float4(fmaxf((p.x+h[0])*0.5f,0.f), fmaxf((p.y+h[1])*0.5f,0.f),
                              fmaxf((p.z+h[2])*0.5f,0.f), fmaxf((p.w+h[3])*0.5f,0.f));
  }
}

__global__ __launch_bounds__(256) void matvec(const float* __restrict__ X,
    const float* __restrict__ w, const float* __restrict__ bias,
    float* __restrict__ o, int N){
  int r = blockIdx.x*4 + (threadIdx.x >> 6);
  if (r >= N) return;
  int lane = threadIdx.x & 63;
  float4 x  = *(const float4*)(X + (size_t)r*256 + lane*4);
  float4 ww = *(const float4*)(w + lane*4);
  float d = x.x*ww.x + x.y*ww.y + x.z*ww.z + x.w*ww.w;
#pragma unroll
  for (int off=32; off; off>>=1) d += __shfl_xor(d, off);
  if (lane == 0) o[r] = d + bias[0];
}

// att_W [4,512,128] -> Wcat [512, 512] with Wcat[d][h*128+k] = att_W[h][d][k]
__global__ void repack_attw(const float* __restrict__ W, float* __restrict__ o){
  int idx = blockIdx.x*256 + threadIdx.x;
  if (idx >= 4*512*128) return;
  int h = idx >> 16, rem = idx & 65535;
  int d = rem >> 7, k = rem & 127;
  o[(size_t)d*512 + h*128 + k] = W[idx];
}

// Whh [1024,256] -> out [256,1024]
__global__ void transpose_wh(const float* __restrict__ in, float* __restrict__ out){
  __shared__ float t[32][33];
  int rb = blockIdx.x*32, cb = blockIdx.y*32;
  int tx = threadIdx.x, ty = threadIdx.y;
  for (int i=0;i<32;i+=8) t[ty+i][tx] = in[(size_t)(rb+ty+i)*256 + cb+tx];
  __syncthreads();
  for (int i=0;i<32;i+=8) out[(size_t)(cb+ty+i)*1024 + rb+tx] = t[tx][ty+i];
}

// ---------------------------------------------------------------------------
extern "C" void kernel_launch(void* const* d_in, const int* in_sizes, int n_in,
                              void* d_out, int out_size, void* d_ws, size_t ws_size,
                              hipStream_t stream)
{
  const float* x_spot = (const float*)d_in[0];
  const float* x_user = (const float*)d_in[1];
  const float* attW   = (const float*)d_in[2];
  const float* attq   = (const float*)d_in[3];
  const float* Wsrc0[3] = { (const float*)d_in[4], (const float*)d_in[5], (const float*)d_in[6] };
  const float* Wtgt0[3] = { (const float*)d_in[7], (const float*)d_in[8], (const float*)d_in[9] };
  const float* Wih0 = (const float*)d_in[10];
  const float* Whh0 = (const float*)d_in[11];
  const float* b0   = (const float*)d_in[12];
  const float* Wsrc1 = (const float*)d_in[13];
  const float* Wtgt1 = (const float*)d_in[14];
  const float* Wih1 = (const float*)d_in[15];
  const float* Whh1 = (const float*)d_in[16];
  const float* b1   = (const float*)d_in[17];
  const float* linSW = (const float*)d_in[18];
  const float* linSb = (const float*)d_in[19];
  const float* linUW = (const float*)d_in[20];
  const float* linUb = (const float*)d_in[21];
  const int* src_us = (const int*)d_in[22];
  const int* dst_us = (const int*)d_in[23];
  const int* src_su = (const int*)d_in[24];
  const int* dst_su = (const int*)d_in[25];
  const int* src_ss = (const int*)d_in[26];
  const int* dst_ss = (const int*)d_in[27];
  float* out = (float*)d_out;
  float* ws  = (float*)d_ws;
  int*   wsi = (int*)d_ws;

  // ---- workspace layout (float offsets) ----
  const size_t WCAT = 0;              // 512*512
  const size_t BC00 = 262144;         // [768,1024]
  const size_t BC01 = 1048576;        // [512,1024]
  const size_t BC02 = 1572864;        // [768,1024]
  const size_t BC10 = 2359296;        // [512,1024]
  const size_t BC11 = 2883584;
  const size_t BC12 = 3407872;
  const size_t X0S  = 3932160;        // [20000,512]
  const size_t SCR  = 14172160;       // 12.8M floats scratch
  const size_t AGG0 = 26972160;       // [20000,256]
  const size_t AGG1 = 32092160;       // [40000,256]
  const size_t AGG2 = 42332160;       // [20000,256]
  const size_t METAS= 47452160;       // [20000,256]
  const size_t X1S  = 52572160;
  const size_t X1U  = 57692160;
  const size_t X2S  = 67932160;
  const size_t X2U  = 78172160;
  const size_t IB   = 88412160;       // int area (int offsets rel. to IB)
  const int OF_US = 0,      CU_US = 20001,  SR_US = 40001;
  const int OF_SU = 240001, CU_SU = 280002, SR_SU = 320002;
  const int OF_SS = 520002, CU_SS = 540003, SR_SS = 560003;
  // bf16 plane area (ushort units, base at float offset 89112160)
  u16* hb = (u16*)(ws + 89112160);
  size_t ho = 0;
  auto halloc = [&](size_t kn)->size_t{ size_t r = ho; ho += 2*kn; return r; };
  const size_t H_WCAT = halloc(512*512);
  const size_t H_US0  = halloc(256*256);
  const size_t H_SU0  = halloc(512*256);
  const size_t H_SS0  = halloc(512*256);
  const size_t H_US1  = halloc(256*256);
  const size_t H_SU1  = halloc(256*256);
  const size_t H_SS1  = halloc(256*256);
  const size_t H_BC[6] = { halloc(768*1024), halloc(512*1024), halloc(768*1024),
                           halloc(512*1024), halloc(512*1024), halloc(512*1024) };

  // ---- phase 0: weight prep ----
  repack_attw<<<1024,256,0,stream>>>(attW, ws+WCAT);
  btrans<<<dim3(16,16),dim3(32,8),0,stream>>>(ws+WCAT, 512, 512, hb+H_WCAT, hb+H_WCAT+512*512);
  // src weights (direct inputs)
  btrans<<<dim3(8,8),  dim3(32,8),0,stream>>>(Wsrc0[0], 256, 256, hb+H_US0, hb+H_US0+256*256);
  btrans<<<dim3(16,8), dim3(32,8),0,stream>>>(Wsrc0[1], 512, 256, hb+H_SU0, hb+H_SU0+512*256);
  btrans<<<dim3(16,8), dim3(32,8),0,stream>>>(Wsrc0[2], 512, 256, hb+H_SS0, hb+H_SS0+512*256);
  btrans<<<dim3(8,8),  dim3(32,8),0,stream>>>(Wsrc1,        256, 256, hb+H_US1, hb+H_US1+256*256);
  btrans<<<dim3(8,8),  dim3(32,8),0,stream>>>(Wsrc1+65536,  256, 256, hb+H_SU1, hb+H_SU1+256*256);
  btrans<<<dim3(8,8),  dim3(32,8),0,stream>>>(Wsrc1+131072, 256, 256, hb+H_SS1, hb+H_SS1+256*256);
  // B_cat = [Wtgt @ Wih^T ; Whh^T]  -> bf16 planes
  struct { const float* Wt; int Kt; const float* Wi; const float* Wh; size_t bc; } cfg[6] = {
    { Wtgt0[0], 512, Wih0,        Whh0,        BC00 },
    { Wtgt0[1], 256, Wih0+262144, Whh0+262144, BC01 },
    { Wtgt0[2], 512, Wih0+524288, Whh0+524288, BC02 },
    { Wtgt1,        256, Wih1,        Whh1,        BC10 },
    { Wtgt1+65536,  256, Wih1+262144, Whh1+262144, BC11 },
    { Wtgt1+131072, 256, Wih1+524288, Whh1+524288, BC12 },
  };
  for (int i=0;i<6;i++){
    dim3 g((cfg[i].Kt+127)/128, 8);
    gemm_wt<<<g,256,0,stream>>>(cfg[i].Wt, 256, cfg[i].Wi, ws+cfg[i].bc, cfg[i].Kt, 1024);
    transpose_wh<<<dim3(32,8),dim3(32,8),0,stream>>>(cfg[i].Wh,
                                  ws+cfg[i].bc + (size_t)cfg[i].Kt*1024);
    int KB = cfg[i].Kt + 256;
    btrans<<<dim3(KB/32,32),dim3(32,8),0,stream>>>(ws+cfg[i].bc, KB, 1024,
                                  hb+H_BC[i], hb+H_BC[i] + (size_t)KB*1024);
  }

  // ---- phase 1: attention pooling -> X0S (4 chunks of 5000 spots) ----
  for (int c=0;c<4;c++){
    gemm_mfma<<<dim3(196,4),256,0,stream>>>(x_spot + (size_t)c*12800000, 512,
                x_spot, 0, hb+H_WCAT, hb+H_WCAT+512*512, ws+SCR, 25000, 512);
    att_pool<<<1250,256,0,stream>>>(ws+SCR, attq, ws+X0S + (size_t)c*2560000, 5000);
  }

  // ---- phase 2: CSR for 3 edge types ----
  struct { const int* src; const int* dst; int E; int Nt; int of, cu, sr; } et[3] = {
    { src_us, dst_us, 200000, 20000, OF_US, CU_US, SR_US },
    { src_su, dst_su, 200000, 40000, OF_SU, CU_SU, SR_SU },
    { src_ss, dst_ss, 100000, 20000, OF_SS, CU_SS, SR_SS },
  };
  for (int i=0;i<3;i++){
    fillz<<<(et[i].Nt+255)/256,256,0,stream>>>(wsi+IB+et[i].cu, et[i].Nt);
    hist_k<<<(et[i].E+255)/256,256,0,stream>>>(et[i].dst, wsi+IB+et[i].cu, et[i].E);
    scan_k<<<1,1024,0,stream>>>(wsi+IB+et[i].cu, wsi+IB+et[i].of, et[i].Nt);
    place_k<<<(et[i].E+255)/256,256,0,stream>>>(et[i].src, et[i].dst,
                                                wsi+IB+et[i].cu, wsi+IB+et[i].sr, et[i].E);
  }

  // ---- layers ----
  for (int L=0; L<2; L++){
    const float* xs = (L==0) ? ws+X0S : ws+X1S;
    const float* xu = (L==0) ? x_user : ws+X1U;
    int Ks = (L==0) ? 512 : 256;
    size_t hUS = (L==0)?H_US0:H_US1, hSU = (L==0)?H_SU0:H_SU1, hSS = (L==0)?H_SS0:H_SS1;
    const size_t* hbc = (L==0) ? &H_BC[0] : &H_BC[3];
    int KB0 = Ks+256, KB1 = 512, KB2 = Ks+256;  // B_cat K per edge type
    const float* bb = (L==0) ? b0 : b1;
    float* outS = (L==0) ? ws+X1S : ws+X2S;
    float* outU = (L==0) ? ws+X1U : ws+X2U;

    // src GEMMs + scatter-max
    gemm_mfma<<<dim3(313,2),256,0,stream>>>(xu, 256, xu, 0,
                hb+hUS, hb+hUS+256*256, ws+SCR, 40000, 256);
    seg_max<<<5000,256,0,stream>>>(ws+SCR, wsi+IB+OF_US, wsi+IB+SR_US, ws+AGG0, 20000);
    gemm_mfma<<<dim3(157,2),256,0,stream>>>(xs, Ks, xs, 0,
                hb+hSU, hb+hSU+(size_t)Ks*256, ws+SCR, 20000, 256);
    seg_max<<<10000,256,0,stream>>>(ws+SCR, wsi+IB+OF_SU, wsi+IB+SR_SU, ws+AGG1, 40000);
    gemm_mfma<<<dim3(157,2),256,0,stream>>>(xs, Ks, xs, 0,
                hb+hSS, hb+hSS+(size_t)Ks*256, ws+SCR, 20000, 256);
    seg_max<<<5000,256,0,stream>>>(ws+SCR, wsi+IB+OF_SS, wsi+IB+SR_SS, ws+AGG2, 20000);
    avg2<<<5000,256,0,stream>>>(ws+AGG0, ws+AGG2, ws+METAS, 1280000);

    // LSTM per edge type: g = [x_t | agg] @ B_cat, then gates
    for (int ch=0; ch<2; ch++){
      gemm_mfma<<<dim3(79,8),256,0,stream>>>(xs + (size_t)ch*10000*Ks, Ks,
            ws+AGG0 + (size_t)ch*10000*256, 256,
            hb+hbc[0], hb+hbc[0]+(size_t)KB0*1024, ws+SCR, 10000, 1024);
      lstm_ew<<<2500,256,0,stream>>>(ws+SCR, bb+0, ws+METAS, outS, 10000, ch*10000, 0);
    }
    for (int ch=0; ch<4; ch++){
      gemm_mfma<<<dim3(79,8),256,0,stream>>>(xu + (size_t)ch*10000*256, 256,
            ws+AGG1 + (size_t)ch*10000*256, 256,
            hb+hbc[1], hb+hbc[1]+(size_t)KB1*1024, ws+SCR, 10000, 1024);
      lstm_ew<<<2500,256,0,stream>>>(ws+SCR, bb+1024, ws+AGG1, outU, 10000, ch*10000, 1);
    }
    for (int ch=0; ch<2; ch++){
      gemm_mfma<<<dim3(79,8),256,0,stream>>>(xs + (size_t)ch*10000*Ks, Ks,
            ws+AGG2 + (size_t)ch*10000*256, 256,
            hb+hbc[2], hb+hbc[2]+(size_t)KB2*1024, ws+SCR, 10000, 1024);
      lstm_ew<<<2500,256,0,stream>>>(ws+SCR, bb+2048, ws+METAS, outS, 10000, ch*10000, 2);
    }
    (void)KB2;
  }

  // ---- outputs ----
  avg2<<<5000,256,0,stream>>>(ws+X1S, ws+X2S, out, 1280000);
  avg2<<<10000,256,0,stream>>>(ws+X1U, ws+X2U, out+5120000, 2560000);
  matvec<<<5000,256,0,stream>>>(ws+X2S, linSW, linSb, out+15360000, 20000);
  matvec<<<10000,256,0,stream>>>(ws+X2U, linUW, linUb, out+15380000, 40000);

  (void)in_sizes; (void)n_in; (void)out_size; (void)ws_size; (void)attq;
}

// Round 4
// 2480.860 us; speedup vs baseline: 2.0367x; 1.2346x over previous
//
#include <hip/hip_runtime.h>
#include <math.h>

// ---------------------------------------------------------------------------
// HeteroDLSTM forward. r4: pre-converted tiled bf16 hi/lo planes +
// global_load_lds MFMA GEMM (3-pass split-float, unchanged numerics).
// NS=20000, NU=40000, E_us=200000, E_su=200000, E_ss=100000. ws ~= 819 MB.
// ---------------------------------------------------------------------------

typedef unsigned short u16;
typedef short short8 __attribute__((ext_vector_type(8)));
typedef float f32x4 __attribute__((ext_vector_type(4)));

__device__ __forceinline__ float fsig(float x){ return 1.f/(1.f+__expf(-x)); }
__device__ __forceinline__ float ftanh(float x){ return 1.f - 2.f/(1.f+__expf(2.f*x)); }
__device__ __forceinline__ u16 bf16rne(float x){
  unsigned u = __float_as_uint(x);
  unsigned r = (u + 0x7FFFu + ((u>>16)&1u)) >> 16;
  return (u16)r;
}
__device__ __forceinline__ void gload16(const void* g, void* l){
  __builtin_amdgcn_global_load_lds(
      (const __attribute__((address_space(1))) unsigned int*)g,
      (__attribute__((address_space(3))) unsigned int*)l, 16, 0, 0);
}

// ---------------- fp32 GEMM (weight prep only): C = A @ B^T ----------------
__global__ __launch_bounds__(256) void gemm_wt(
    const float* __restrict__ A1, int K,
    const float* __restrict__ Bg,
    float* __restrict__ C, int M, int N)
{
  __shared__ float As[16][132];
  __shared__ float Bs[16][132];
  const int bm = blockIdx.x * 128;
  const int bn = blockIdx.y * 128;
  const int tid = threadIdx.x;
  const int tx = tid & 15, ty = tid >> 4;
  float acc[8][8];
#pragma unroll
  for (int i=0;i<8;i++)
#pragma unroll
    for (int j=0;j<8;j++) acc[i][j]=0.f;
  for (int k0 = 0; k0 < K; k0 += 16) {
#pragma unroll
    for (int i=0;i<2;i++) {
      int f = tid + i*256;
      int ar = f >> 2, ac = (f & 3) << 2;
      int grow = bm + ar, kk = k0 + ac;
      float4 v = make_float4(0.f,0.f,0.f,0.f);
      if (grow < M) v = *(const float4*)(A1 + (size_t)grow*K + kk);
      As[ac+0][ar]=v.x; As[ac+1][ar]=v.y; As[ac+2][ar]=v.z; As[ac+3][ar]=v.w;
    }
#pragma unroll
    for (int i=0;i<2;i++) {
      int f = tid + i*256;
      int nn = f >> 2, kc = (f & 3) << 2;
      float4 v = *(const float4*)(Bg + (size_t)(bn+nn)*K + k0 + kc);
      Bs[kc+0][nn]=v.x; Bs[kc+1][nn]=v.y; Bs[kc+2][nn]=v.z; Bs[kc+3][nn]=v.w;
    }
    __syncthreads();
#pragma unroll
    for (int k=0;k<16;k++) {
      float a[8], b[8];
      *(float4*)&a[0] = *(float4*)&As[k][ty*4];
      *(float4*)&a[4] = *(float4*)&As[k][ty*4+64];
      *(float4*)&b[0] = *(float4*)&Bs[k][tx*4];
      *(float4*)&b[4] = *(float4*)&Bs[k][tx*4+64];
#pragma unroll
      for (int i=0;i<8;i++)
#pragma unroll
        for (int j=0;j<8;j++)
          acc[i][j] = fmaf(a[i], b[j], acc[i][j]);
    }
    __syncthreads();
  }
#pragma unroll
  for (int ih=0; ih<2; ih++)
#pragma unroll
    for (int i=0;i<4;i++) {
      int r = bm + ty*4 + i + ih*64;
      if (r < M) {
        float* Cr = C + (size_t)r*N + bn;
        *(float4*)(Cr + tx*4)      = *(float4*)&acc[ih*4+i][0];
        *(float4*)(Cr + tx*4 + 64) = *(float4*)&acc[ih*4+i][4];
      }
    }
}

// ---- activation convert: fp32 [Rv,K] row-major -> tiled bf16 hi/lo planes ----
// plane layout: [tile=r/128][ks=k/8][r%128][e=k%8]; pad rows -> 0.
__global__ __launch_bounds__(256) void cvt_tile(
    const float* __restrict__ in, int Rv, int K,
    u16* __restrict__ Ph, u16* __restrict__ Pl)
{
  int t = blockIdx.x;
  int row = threadIdx.x & 127;
  int ksh = threadIdx.x >> 7;
  int grow = t*128 + row;
  bool v = grow < Rv;
  const float* src = in + (size_t)grow*K;
  size_t pb = (size_t)t*K*128;
  int NKS = K >> 3;
  for (int ks = ksh; ks < NKS; ks += 2){
    float x[8];
    if (v){
      float4 a = *(const float4*)(src + ks*8);
      float4 b = *(const float4*)(src + ks*8 + 4);
      x[0]=a.x;x[1]=a.y;x[2]=a.z;x[3]=a.w;x[4]=b.x;x[5]=b.y;x[6]=b.z;x[7]=b.w;
    } else {
#pragma unroll
      for (int j=0;j<8;j++) x[j]=0.f;
    }
    short8 h,l;
#pragma unroll
    for (int j=0;j<8;j++){
      u16 hh = bf16rne(x[j]);
      h[j] = (short)hh;
      l[j] = (short)bf16rne(x[j] - __uint_as_float(((unsigned)hh)<<16));
    }
    size_t o = pb + (size_t)ks*1024 + row*8;
    *(short8*)&Ph[o] = h;
    *(short8*)&Pl[o] = l;
  }
}

// ---- weight convert: fp32 [K][N] -> tiled bf16 hi/lo planes over n-rows ----
__global__ void btrans_t(const float* __restrict__ in, int K, int N,
                         u16* __restrict__ Ph, u16* __restrict__ Pl){
  __shared__ float t[32][33];
  int k0 = blockIdx.x*32, n0 = blockIdx.y*32;
  int tx = threadIdx.x, ty = threadIdx.y;
  for (int r=0;r<32;r+=8) t[ty+r][tx] = in[(size_t)(k0+ty+r)*N + n0+tx];
  __syncthreads();
  for (int r=0;r<32;r+=8){
    int n = n0+ty+r, k = k0+tx;
    float x = t[tx][ty+r];
    u16 h = bf16rne(x);
    u16 lo = bf16rne(x - __uint_as_float(((unsigned)h)<<16));
    size_t off = (size_t)(n>>7)*K*128 + (size_t)(k>>3)*1024 + (size_t)(n&127)*8 + (k&7);
    Ph[off]=h; Pl[off]=lo;
  }
}

// ---------------- bf16x2 MFMA GEMM, global_load_lds staging ----------------
// C[M,N] = [A1 | A2] @ B ; all operands pre-converted tiled planes.
// 128x128 tile, BK=32, 4 waves; wave w stages plane w (Ah,Al,Bh,Bl).
__global__ __launch_bounds__(256) void gemm3p(
    const u16* __restrict__ A1h, const u16* __restrict__ A1l, int K1,
    const u16* __restrict__ A2h, const u16* __restrict__ A2l, int K2,
    const u16* __restrict__ Bh,  const u16* __restrict__ Bl,
    float* __restrict__ C, int M, int N)
{
  const int KB = K1 + K2;
  __shared__ u16 S[4][4096];
  const int tid = threadIdx.x;
  const int tm = blockIdx.x, tn = blockIdx.y;
  const int w = tid >> 6, l = tid & 63;
  const int wr = w >> 1, wc = w & 1;
  const int lm = l & 15, lk = l >> 4;

  f32x4 acc[4][4];
#pragma unroll
  for (int i=0;i<4;i++)
#pragma unroll
    for (int j=0;j<4;j++) acc[i][j] = (f32x4){0.f,0.f,0.f,0.f};

  const size_t sA1 = (size_t)tm*K1*128, sA2 = (size_t)tm*K2*128, sB = (size_t)tn*KB*128;

  for (int k0 = 0; k0 < KB; k0 += 32) {
    const u16* gp;
    if (w==0)      gp = (k0<K1) ? A1h + sA1 + (size_t)k0*128 : A2h + sA2 + (size_t)(k0-K1)*128;
    else if (w==1) gp = (k0<K1) ? A1l + sA1 + (size_t)k0*128 : A2l + sA2 + (size_t)(k0-K1)*128;
    else if (w==2) gp = Bh + sB + (size_t)k0*128;
    else           gp = Bl + sB + (size_t)k0*128;
    const char* g = (const char*)gp + (l<<4);
    u16* lp = &S[w][0];
#pragma unroll
    for (int i=0;i<8;i++)
      gload16(g + i*1024, lp + i*512);
    __syncthreads();   // drains vmcnt before barrier (compiler-inserted)
    short8 ah[4], al[4], bh[4], bl[4];
#pragma unroll
    for (int i=0;i<4;i++){
      int ra = lk*1024 + (wr*64 + i*16 + lm)*8;
      ah[i] = *(short8*)&S[0][ra];
      al[i] = *(short8*)&S[1][ra];
      int rb = lk*1024 + (wc*64 + i*16 + lm)*8;
      bh[i] = *(short8*)&S[2][rb];
      bl[i] = *(short8*)&S[3][rb];
    }
#pragma unroll
    for (int i=0;i<4;i++)
#pragma unroll
      for (int j=0;j<4;j++){
        acc[i][j] = __builtin_amdgcn_mfma_f32_16x16x32_bf16(ah[i], bh[j], acc[i][j], 0,0,0);
        acc[i][j] = __builtin_amdgcn_mfma_f32_16x16x32_bf16(ah[i], bl[j], acc[i][j], 0,0,0);
        acc[i][j] = __builtin_amdgcn_mfma_f32_16x16x32_bf16(al[i], bh[j], acc[i][j], 0,0,0);
      }
    __syncthreads();
  }
  const int bm = tm*128, bn = tn*128;
#pragma unroll
  for (int i=0;i<4;i++){
    int row0 = bm + wr*64 + i*16 + lk*4;
#pragma unroll
    for (int r=0;r<4;r++){
      int row = row0 + r;
      if (row < M){
        float* Cr = C + (size_t)row*N + bn + wc*64 + lm;
#pragma unroll
        for (int j=0;j<4;j++) Cr[j*16] = acc[i][j][r];
      }
    }
  }
}

// ---------------- attention pooling (after C1 = X@Wcat) ----------------
__global__ __launch_bounds__(256) void att_pool(
    const float* __restrict__ C1, const float* __restrict__ q,
    float* __restrict__ outp, int ns)
{
  __shared__ float xh[20*512];
  int b0 = blockIdx.x * 4;
  int nrows = (ns - b0) * 5; if (nrows > 20) nrows = 20; if (nrows < 0) nrows = 0;
  for (int f = threadIdx.x; f < 2560; f += 256) {
    int row = f >> 7, c4 = (f & 127) << 2;
    float4 v = make_float4(0.f,0.f,0.f,0.f);
    if (row < nrows) v = *(const float4*)(C1 + (size_t)(b0*5+row)*512 + c4);
    *(float4*)&xh[row*512 + c4] = v;
  }
  __syncthreads();
  int wid = threadIdx.x >> 6, lane = threadIdx.x & 63;
  int n = b0 + wid;
  if (n >= ns) return;
  const float* X = &xh[wid*5*512];
  float att[4][5];
#pragma unroll
  for (int h=0; h<4; h++) {
#pragma unroll
    for (int s=0; s<5; s++) {
      float d = X[s*512 + h*128 + lane]      * q[h*128 + lane]
              + X[s*512 + h*128 + 64 + lane] * q[h*128 + 64 + lane];
#pragma unroll
      for (int off=32; off; off>>=1) d += __shfl_xor(d, off);
      att[h][s] = d > 0.f ? d : 0.2f*d;
    }
    float m = att[h][0];
#pragma unroll
    for (int s=1;s<5;s++) m = fmaxf(m, att[h][s]);
    float sum = 0.f;
#pragma unroll
    for (int s=0;s<5;s++){ att[h][s] = __expf(att[h][s]-m); sum += att[h][s]; }
    float inv = 1.f/sum;
#pragma unroll
    for (int s=0;s<5;s++) att[h][s] *= inv;
  }
  int c0 = lane * 8;
  int h = c0 >> 7;
  float o[8] = {0,0,0,0,0,0,0,0};
#pragma unroll
  for (int s=0;s<5;s++) {
    float w = att[h][s];
    const float* Xr = X + s*512 + c0;
#pragma unroll
    for (int j=0;j<8;j++) o[j] = fmaf(w, Xr[j], o[j]);
  }
  float* op = outp + (size_t)n*512 + c0;
  *(float4*)op     = *(float4*)&o[0];
  *(float4*)(op+4) = *(float4*)&o[4];
}

// ---------------- CSR build ----------------
__global__ void fillz(int* __restrict__ p, int n){
  int i = blockIdx.x*256 + threadIdx.x; if (i < n) p[i] = 0;
}
__global__ void hist_k(const int* __restrict__ dst, int* __restrict__ cnt, int E){
  int e = blockIdx.x*256 + threadIdx.x; if (e < E) atomicAdd(&cnt[dst[e]], 1);
}
__global__ void scan_k(int* __restrict__ cnt, int* __restrict__ offs, int n){
  __shared__ int sm[1024];
  int tid = threadIdx.x;
  int running = 0;
  for (int base = 0; base < n; base += 1024) {
    int i = base + tid;
    int v = (i < n) ? cnt[i] : 0;
    sm[tid] = v;
    __syncthreads();
    for (int off=1; off<1024; off<<=1) {
      int add = (tid >= off) ? sm[tid-off] : 0;
      __syncthreads();
      sm[tid] += add;
      __syncthreads();
    }
    int incl = sm[tid];
    int tot  = sm[1023];
    int excl = running + incl - v;
    if (i < n) { offs[i] = excl; cnt[i] = excl; }
    running += tot;
    __syncthreads();
  }
  if (tid == 0) offs[n] = running;
}
__global__ void place_k(const int* __restrict__ src, const int* __restrict__ dst,
                        int* __restrict__ cur, int* __restrict__ srt, int E){
  int e = blockIdx.x*256 + threadIdx.x;
  if (e < E) { int p = atomicAdd(&cur[dst[e]], 1); srt[p] = src[e]; }
}

// ---------------- segment max (empty -> 0) ----------------
__global__ __launch_bounds__(256) void seg_max(
    const float* __restrict__ S, const int* __restrict__ offs,
    const int* __restrict__ ssrc, float* __restrict__ agg, int Nt)
{
  int t = blockIdx.x*4 + (threadIdx.x >> 6);
  if (t >= Nt) return;
  int lane = threadIdx.x & 63;
  int e0 = offs[t], e1 = offs[t+1];
  float4 m = make_float4(-INFINITY,-INFINITY,-INFINITY,-INFINITY);
  for (int e = e0; e < e1; e++) {
    int s = ssrc[e];
    float4 v = *(const float4*)(S + (size_t)s*256 + lane*4);
    m.x = fmaxf(m.x,v.x); m.y = fmaxf(m.y,v.y); m.z = fmaxf(m.z,v.z); m.w = fmaxf(m.w,v.w);
  }
  if (e1 == e0) m = make_float4(0.f,0.f,0.f,0.f);
  *(float4*)(agg + (size_t)t*256 + lane*4) = m;
}

// ---------------- misc elementwise ----------------
__global__ void avg2(const float* __restrict__ a, const float* __restrict__ b,
                     float* __restrict__ o, int n4){
  int i = blockIdx.x*256 + threadIdx.x;
  if (i < n4) {
    float4 x = ((const float4*)a)[i], y = ((const float4*)b)[i];
    float4 r; r.x=(x.x+y.x)*0.5f; r.y=(x.y+y.y)*0.5f; r.z=(x.z+y.z)*0.5f; r.w=(x.w+y.w)*0.5f;
    ((float4*)o)[i] = r;
  }
}

// LSTM gates; 64-lane group per row, float4 per thread.
// mode 0: out=h ; mode 1: out=relu(h) ; mode 2: out=relu((out+h)*0.5)
__global__ __launch_bounds__(256) void lstm_ew(
    const float* __restrict__ g, const float* __restrict__ b,
    const float* __restrict__ c_in, float* __restrict__ outp,
    int rows, int r0, int mode)
{
  int n = blockIdx.x*4 + (threadIdx.x >> 6);
  if (n >= rows) return;
  int j = (threadIdx.x & 63) * 4;
  const float* gr = g + (size_t)n*1024;
  float4 ig = *(const float4*)(gr + j);
  float4 fg = *(const float4*)(gr + 256 + j);
  float4 gg = *(const float4*)(gr + 512 + j);
  float4 og = *(const float4*)(gr + 768 + j);
  float4 bi = *(const float4*)(b + j);
  float4 bf = *(const float4*)(b + 256 + j);
  float4 bg = *(const float4*)(b + 512 + j);
  float4 bo = *(const float4*)(b + 768 + j);
  float4 c  = *(const float4*)(c_in + (size_t)(r0+n)*256 + j);
  float h[4];
  {
    float c2;
    c2 = fsig(fg.x+bf.x)*c.x + fsig(ig.x+bi.x)*ftanh(gg.x+bg.x); h[0] = fsig(og.x+bo.x)*ftanh(c2);
    c2 = fsig(fg.y+bf.y)*c.y + fsig(ig.y+bi.y)*ftanh(gg.y+bg.y); h[1] = fsig(og.y+bo.y)*ftanh(c2);
    c2 = fsig(fg.z+bf.z)*c.z + fsig(ig.z+bi.z)*ftanh(gg.z+bg.z); h[2] = fsig(og.z+bo.z)*ftanh(c2);
    c2 = fsig(fg.w+bf.w)*c.w + fsig(ig.w+bi.w)*ftanh(gg.w+bg.w); h[3] = fsig(og.w+bo.w)*ftanh(c2);
  }
  float* o = outp + (size_t)(r0+n)*256 + j;
  if (mode == 0) {
    *(float4*)o = make_float4(h[0],h[1],h[2],h[3]);
  } else if (mode == 1) {
    *(float4*)o = make_float4(fmaxf(h[0],0.f),fmaxf(h[1],0.f),fmaxf(h[2],0.f),fmaxf(h[3],0.f));
  } else {
    float4 p = *(const float4*)o;
    *(float4*)o = make_float4(fmaxf((p.x+h[0])*0.5f,0.f), fmaxf((p.y+h[1])*0.5f,0.f),
                              fmaxf((p.z+h[2])*0.5f,0.f), fmaxf((p.w+h[3])*0.5f,0.f));
  }
}

__global__ __launch_bounds__(256) void matvec(const float* __restrict__ X,
    const float* __restrict__ w, const float* __restrict__ bias,
    float* __restrict__ o, int N){
  int r = blockIdx.x*4 + (threadIdx.x >> 6);
  if (r >= N) return;
  int lane = threadIdx.x & 63;
  float4 x  = *(const float4*)(X + (size_t)r*256 + lane*4);
  float4 ww = *(const float4*)(w + lane*4);
  float d = x.x*ww.x + x.y*ww.y + x.z*ww.z + x.w*ww.w;
#pragma unroll
  for (int off=32; off; off>>=1) d += __shfl_xor(d, off);
  if (lane == 0) o[r] = d + bias[0];
}

// att_W [4,512,128] -> Wcat [512, 512] with Wcat[d][h*128+k] = att_W[h][d][k]
__global__ void repack_attw(const float* __restrict__ W, float* __restrict__ o){
  int idx = blockIdx.x*256 + threadIdx.x;
  if (idx >= 4*512*128) return;
  int h = idx >> 16, rem = idx & 65535;
  int d = rem >> 7, k = rem & 127;
  o[(size_t)d*512 + h*128 + k] = W[idx];
}

// Whh [1024,256] -> out [256,1024]
__global__ void transpose_wh(const float* __restrict__ in, float* __restrict__ out){
  __shared__ float t[32][33];
  int rb = blockIdx.x*32, cb = blockIdx.y*32;
  int tx = threadIdx.x, ty = threadIdx.y;
  for (int i=0;i<32;i+=8) t[ty+i][tx] = in[(size_t)(rb+ty+i)*256 + cb+tx];
  __syncthreads();
  for (int i=0;i<32;i+=8) out[(size_t)(cb+ty+i)*1024 + rb+tx] = t[tx][ty+i];
}

// ---------------------------------------------------------------------------
extern "C" void kernel_launch(void* const* d_in, const int* in_sizes, int n_in,
                              void* d_out, int out_size, void* d_ws, size_t ws_size,
                              hipStream_t stream)
{
  const float* x_spot = (const float*)d_in[0];
  const float* x_user = (const float*)d_in[1];
  const float* attW   = (const float*)d_in[2];
  const float* attq   = (const float*)d_in[3];
  const float* Wsrc0[3] = { (const float*)d_in[4], (const float*)d_in[5], (const float*)d_in[6] };
  const float* Wtgt0[3] = { (const float*)d_in[7], (const float*)d_in[8], (const float*)d_in[9] };
  const float* Wih0 = (const float*)d_in[10];
  const float* Whh0 = (const float*)d_in[11];
  const float* b0   = (const float*)d_in[12];
  const float* Wsrc1 = (const float*)d_in[13];
  const float* Wtgt1 = (const float*)d_in[14];
  const float* Wih1 = (const float*)d_in[15];
  const float* Whh1 = (const float*)d_in[16];
  const float* b1   = (const float*)d_in[17];
  const float* linSW = (const float*)d_in[18];
  const float* linSb = (const float*)d_in[19];
  const float* linUW = (const float*)d_in[20];
  const float* linUb = (const float*)d_in[21];
  const int* src_us = (const int*)d_in[22];
  const int* dst_us = (const int*)d_in[23];
  const int* src_su = (const int*)d_in[24];
  const int* dst_su = (const int*)d_in[25];
  const int* src_ss = (const int*)d_in[26];
  const int* dst_ss = (const int*)d_in[27];
  float* out = (float*)d_out;
  float* ws  = (float*)d_ws;
  int*   wsi = (int*)d_ws;

  // ---- float workspace layout (float offsets) ----
  const size_t SCR   = 0;          // 20.6M floats (C1 chunk / src S / g)
  const size_t X0S   = 20600000;   // [20000,512]
  const size_t AGG0  = 30840000;   // [20000,256]
  const size_t AGG1  = 35960000;   // [40000,256]
  const size_t AGG2  = 46200000;   // [20000,256]
  const size_t METAS = 51320000;   // [20000,256]
  const size_t X1S   = 56440000;
  const size_t X1U   = 61560000;
  const size_t X2S   = 71800000;
  const size_t X2U   = 82040000;
  const size_t BCF   = 92280000;   // [<=1024,1024] fp32 B_cat build scratch
  const size_t WCATF = 93328576;   // [512,512]
  const size_t IBASE = 93600000;   // int area
  const int OF_US = 0,      CU_US = 20001,  SR_US = 40001;
  const int OF_SU = 240001, CU_SU = 280002, SR_SU = 320002;
  const int OF_SS = 520002, CU_SS = 540003, SR_SS = 560003;
  int* ib = wsi + IBASE;

  // ---- bf16 tiled-plane area (u16 element offsets from hb) ----
  u16* hb = (u16*)(ws + 94300000);
  const size_t ATT_A  = 0;          // 25088x512 x2 = 25,690,112
  const size_t ATT_AH = 12845056;   // half (lo offset)
  const size_t WCATP  = 25690112;   // 512x512 x2
  const size_t WSPB   = 26214400;   // src-weight planes
  const size_t WUS0 = WSPB+0,      WSU0 = WSPB+131072, WSS0 = WSPB+393216;
  const size_t WUS1 = WSPB+655360, WSU1 = WSPB+786432, WSS1 = WSPB+917504;
  const size_t BCPB = 27262976;
  const size_t BCP[6] = { BCPB+0, BCPB+1572864, BCPB+2621440,
                          BCPB+4194304, BCPB+5242880, BCPB+6291456 };
  const size_t XS_P = 34603008;     // 20096 x <=512 x2
  const size_t XU_P = 55181312;     // 40064 x 256 x2
  const size_t AG0P = 75694080;     // 20096 x 256 x2
  const size_t AG1P = 85983232;     // 40064 x 256 x2
  const size_t AG2P = 106496000;    // 20096 x 256 x2

  // ---- phase 0: weight prep ----
  repack_attw<<<1024,256,0,stream>>>(attW, ws+WCATF);
  btrans_t<<<dim3(16,16),dim3(32,8),0,stream>>>(ws+WCATF, 512, 512, hb+WCATP, hb+WCATP+262144);
  btrans_t<<<dim3(8,8),  dim3(32,8),0,stream>>>(Wsrc0[0], 256, 256, hb+WUS0, hb+WUS0+65536);
  btrans_t<<<dim3(16,8), dim3(32,8),0,stream>>>(Wsrc0[1], 512, 256, hb+WSU0, hb+WSU0+131072);
  btrans_t<<<dim3(16,8), dim3(32,8),0,stream>>>(Wsrc0[2], 512, 256, hb+WSS0, hb+WSS0+131072);
  btrans_t<<<dim3(8,8),  dim3(32,8),0,stream>>>(Wsrc1,        256, 256, hb+WUS1, hb+WUS1+65536);
  btrans_t<<<dim3(8,8),  dim3(32,8),0,stream>>>(Wsrc1+65536,  256, 256, hb+WSU1, hb+WSU1+65536);
  btrans_t<<<dim3(8,8),  dim3(32,8),0,stream>>>(Wsrc1+131072, 256, 256, hb+WSS1, hb+WSS1+65536);

  struct { const float* Wt; int Kt; const float* Wi; const float* Wh; } cfg[6] = {
    { Wtgt0[0], 512, Wih0,        Whh0        },
    { Wtgt0[1], 256, Wih0+262144, Whh0+262144 },
    { Wtgt0[2], 512, Wih0+524288, Whh0+524288 },
    { Wtgt1,        256, Wih1,        Whh1        },
    { Wtgt1+65536,  256, Wih1+262144, Whh1+262144 },
    { Wtgt1+131072, 256, Wih1+524288, Whh1+524288 },
  };
  for (int i=0;i<6;i++){
    int Kt = cfg[i].Kt, KB = Kt + 256;
    gemm_wt<<<dim3((Kt+127)/128,8),256,0,stream>>>(cfg[i].Wt, 256, cfg[i].Wi, ws+BCF, Kt, 1024);
    transpose_wh<<<dim3(32,8),dim3(32,8),0,stream>>>(cfg[i].Wh, ws+BCF + (size_t)Kt*1024);
    btrans_t<<<dim3(KB/32,32),dim3(32,8),0,stream>>>(ws+BCF, KB, 1024,
                                  hb+BCP[i], hb+BCP[i] + (size_t)KB*1024);
  }

  // ---- phase 1: attention pooling -> X0S (4 chunks of 5000 spots) ----
  for (int c=0;c<4;c++){
    cvt_tile<<<196,256,0,stream>>>(x_spot + (size_t)c*12800000, 25000, 512,
                                   hb+ATT_A, hb+ATT_A+ATT_AH);
    gemm3p<<<dim3(196,4),256,0,stream>>>(hb+ATT_A, hb+ATT_A+ATT_AH, 512,
                hb+ATT_A, hb+ATT_A+ATT_AH, 0,
                hb+WCATP, hb+WCATP+262144, ws+SCR, 25000, 512);
    att_pool<<<1250,256,0,stream>>>(ws+SCR, attq, ws+X0S + (size_t)c*2560000, 5000);
  }

  // ---- phase 2: CSR for 3 edge types ----
  struct { const int* src; const int* dst; int E; int Nt; int of, cu, sr; } et[3] = {
    { src_us, dst_us, 200000, 20000, OF_US, CU_US, SR_US },
    { src_su, dst_su, 200000, 40000, OF_SU, CU_SU, SR_SU },
    { src_ss, dst_ss, 100000, 20000, OF_SS, CU_SS, SR_SS },
  };
  for (int i=0;i<3;i++){
    fillz<<<(et[i].Nt+255)/256,256,0,stream>>>(ib+et[i].cu, et[i].Nt);
    hist_k<<<(et[i].E+255)/256,256,0,stream>>>(et[i].dst, ib+et[i].cu, et[i].E);
    scan_k<<<1,1024,0,stream>>>(ib+et[i].cu, ib+et[i].of, et[i].Nt);
    place_k<<<(et[i].E+255)/256,256,0,stream>>>(et[i].src, et[i].dst,
                                                ib+et[i].cu, ib+et[i].sr, et[i].E);
  }

  // ---- layers ----
  for (int L=0; L<2; L++){
    const float* xsF = (L==0) ? ws+X0S : ws+X1S;
    const float* xuF = (L==0) ? x_user : ws+X1U;
    int Ks = (L==0) ? 512 : 256;
    const float* bb = (L==0) ? b0 : b1;
    float* outS = (L==0) ? ws+X1S : ws+X2S;
    float* outU = (L==0) ? ws+X1U : ws+X2U;

    u16 *XSh = hb+XS_P, *XSl = XSh + (size_t)20096*Ks;
    u16 *XUh = hb+XU_P, *XUl = XUh + 10256384;
    u16 *A0h = hb+AG0P, *A0l = A0h + 5144576;
    u16 *A1h = hb+AG1P, *A1l = A1h + 10256384;
    u16 *A2h = hb+AG2P, *A2l = A2h + 5144576;
    u16 *WusH = hb + (L?WUS1:WUS0), *WusL = WusH + 65536;
    u16 *WsuH = hb + (L?WSU1:WSU0), *WsuL = WsuH + (size_t)Ks*256;
    u16 *WssH = hb + (L?WSS1:WSS0), *WssL = WssH + (size_t)Ks*256;
    u16 *BC0h = hb + BCP[L?3:0], *BC0l = BC0h + (size_t)(Ks+256)*1024;
    u16 *BC1h = hb + BCP[L?4:1], *BC1l = BC1h + (size_t)512*1024;
    u16 *BC2h = hb + BCP[L?5:2], *BC2l = BC2h + (size_t)(Ks+256)*1024;

    // activation planes
    cvt_tile<<<157,256,0,stream>>>(xsF, 20000, Ks, XSh, XSl);
    cvt_tile<<<313,256,0,stream>>>(xuF, 40000, 256, XUh, XUl);

    // src GEMMs + scatter-max
    gemm3p<<<dim3(313,2),256,0,stream>>>(XUh,XUl,256, XUh,XUl,0, WusH,WusL, ws+SCR, 40000, 256);
    seg_max<<<5000,256,0,stream>>>(ws+SCR, ib+OF_US, ib+SR_US, ws+AGG0, 20000);
    gemm3p<<<dim3(157,2),256,0,stream>>>(XSh,XSl,Ks, XSh,XSl,0, WsuH,WsuL, ws+SCR, 20000, 256);
    seg_max<<<10000,256,0,stream>>>(ws+SCR, ib+OF_SU, ib+SR_SU, ws+AGG1, 40000);
    gemm3p<<<dim3(157,2),256,0,stream>>>(XSh,XSl,Ks, XSh,XSl,0, WssH,WssL, ws+SCR, 20000, 256);
    seg_max<<<5000,256,0,stream>>>(ws+SCR, ib+OF_SS, ib+SR_SS, ws+AGG2, 20000);
    avg2<<<5000,256,0,stream>>>(ws+AGG0, ws+AGG2, ws+METAS, 1280000);

    // agg planes
    cvt_tile<<<157,256,0,stream>>>(ws+AGG0, 20000, 256, A0h, A0l);
    cvt_tile<<<313,256,0,stream>>>(ws+AGG1, 40000, 256, A1h, A1l);
    cvt_tile<<<157,256,0,stream>>>(ws+AGG2, 20000, 256, A2h, A2l);

    // gate GEMM + LSTM: e0 -> spot (mode 0)
    gemm3p<<<dim3(157,8),256,0,stream>>>(XSh,XSl,Ks, A0h,A0l,256, BC0h,BC0l, ws+SCR, 20000, 1024);
    lstm_ew<<<5000,256,0,stream>>>(ws+SCR, bb+0, ws+METAS, outS, 20000, 0, 0);
    // e1 -> user (mode 1), 2 tile-aligned chunks: 19968 + 20032 rows
    gemm3p<<<dim3(156,8),256,0,stream>>>(XUh,XUl,256, A1h,A1l,256, BC1h,BC1l, ws+SCR, 19968, 1024);
    lstm_ew<<<4992,256,0,stream>>>(ws+SCR, bb+1024, ws+AGG1, outU, 19968, 0, 1);
    gemm3p<<<dim3(157,8),256,0,stream>>>(XUh+156*32768, XUl+156*32768, 256,
                A1h+156*32768, A1l+156*32768, 256, BC1h,BC1l, ws+SCR, 20032, 1024);
    lstm_ew<<<5008,256,0,stream>>>(ws+SCR, bb+1024, ws+AGG1, outU, 20032, 19968, 1);
    // e2 -> spot (mode 2)
    gemm3p<<<dim3(157,8),256,0,stream>>>(XSh,XSl,Ks, A2h,A2l,256, BC2h,BC2l, ws+SCR, 20000, 1024);
    lstm_ew<<<5000,256,0,stream>>>(ws+SCR, bb+2048, ws+METAS, outS, 20000, 0, 2);
  }

  // ---- outputs ----
  avg2<<<5000,256,0,stream>>>(ws+X1S, ws+X2S, out, 1280000);
  avg2<<<10000,256,0,stream>>>(ws+X1U, ws+X2U, out+5120000, 2560000);
  matvec<<<5000,256,0,stream>>>(ws+X2S, linSW, linSb, out+15360000, 20000);
  matvec<<<10000,256,0,stream>>>(ws+X2U, linUW, linUb, out+15380000, 40000);

  (void)in_sizes; (void)n_in; (void)out_size; (void)ws_size;
}

// Round 5
// 1883.930 us; speedup vs baseline: 2.6820x; 1.3169x over previous
//
#include <hip/hip_runtime.h>
#include <math.h>

// ---------------------------------------------------------------------------
// HeteroDLSTM forward. r5: single-pass bf16 MFMA + fused LSTM epilogue
// (gate-interleaved B_cat), seg_max/att_pool write bf16 planes directly.
// NS=20000, NU=40000, E_us=200000, E_su=200000, E_ss=100000.
// ---------------------------------------------------------------------------

typedef unsigned short u16;
typedef short short8 __attribute__((ext_vector_type(8)));
typedef float f32x4 __attribute__((ext_vector_type(4)));

__device__ __forceinline__ float fsig(float x){ return 1.f/(1.f+__expf(-x)); }
__device__ __forceinline__ float ftanh(float x){ return 1.f - 2.f/(1.f+__expf(2.f*x)); }
__device__ __forceinline__ u16 bf16rne(float x){
  unsigned u = __float_as_uint(x);
  return (u16)((u + 0x7FFFu + ((u>>16)&1u)) >> 16);
}
__device__ __forceinline__ void gload16(const void* g, void* l){
  __builtin_amdgcn_global_load_lds(
      (const __attribute__((address_space(1))) unsigned int*)g,
      (__attribute__((address_space(3))) unsigned int*)l, 16, 0, 0);
}

// ---------------- fp32 GEMM (weight prep only): C = A @ B^T ----------------
__global__ __launch_bounds__(256) void gemm_wt(
    const float* __restrict__ A1, int K,
    const float* __restrict__ Bg,
    float* __restrict__ C, int M, int N)
{
  __shared__ float As[16][132];
  __shared__ float Bs[16][132];
  const int bm = blockIdx.x * 128;
  const int bn = blockIdx.y * 128;
  const int tid = threadIdx.x;
  const int tx = tid & 15, ty = tid >> 4;
  float acc[8][8];
#pragma unroll
  for (int i=0;i<8;i++)
#pragma unroll
    for (int j=0;j<8;j++) acc[i][j]=0.f;
  for (int k0 = 0; k0 < K; k0 += 16) {
#pragma unroll
    for (int i=0;i<2;i++) {
      int f = tid + i*256;
      int ar = f >> 2, ac = (f & 3) << 2;
      int grow = bm + ar, kk = k0 + ac;
      float4 v = make_float4(0.f,0.f,0.f,0.f);
      if (grow < M) v = *(const float4*)(A1 + (size_t)grow*K + kk);
      As[ac+0][ar]=v.x; As[ac+1][ar]=v.y; As[ac+2][ar]=v.z; As[ac+3][ar]=v.w;
    }
#pragma unroll
    for (int i=0;i<2;i++) {
      int f = tid + i*256;
      int nn = f >> 2, kc = (f & 3) << 2;
      float4 v = *(const float4*)(Bg + (size_t)(bn+nn)*K + k0 + kc);
      Bs[kc+0][nn]=v.x; Bs[kc+1][nn]=v.y; Bs[kc+2][nn]=v.z; Bs[kc+3][nn]=v.w;
    }
    __syncthreads();
#pragma unroll
    for (int k=0;k<16;k++) {
      float a[8], b[8];
      *(float4*)&a[0] = *(float4*)&As[k][ty*4];
      *(float4*)&a[4] = *(float4*)&As[k][ty*4+64];
      *(float4*)&b[0] = *(float4*)&Bs[k][tx*4];
      *(float4*)&b[4] = *(float4*)&Bs[k][tx*4+64];
#pragma unroll
      for (int i=0;i<8;i++)
#pragma unroll
        for (int j=0;j<8;j++)
          acc[i][j] = fmaf(a[i], b[j], acc[i][j]);
    }
    __syncthreads();
  }
#pragma unroll
  for (int ih=0; ih<2; ih++)
#pragma unroll
    for (int i=0;i<4;i++) {
      int r = bm + ty*4 + i + ih*64;
      if (r < M) {
        float* Cr = C + (size_t)r*N + bn;
        *(float4*)(Cr + tx*4)      = *(float4*)&acc[ih*4+i][0];
        *(float4*)(Cr + tx*4 + 64) = *(float4*)&acc[ih*4+i][4];
      }
    }
}

// ---- activation convert: fp32 [Rv,K] -> tiled bf16 plane ----
// layout: [tile=r/128][ks=k/8][r%128][k%8]
__global__ __launch_bounds__(256) void cvt1(
    const float* __restrict__ in, int Rv, int K, u16* __restrict__ Ph)
{
  int t = blockIdx.x;
  int row = threadIdx.x & 127;
  int ksh = threadIdx.x >> 7;
  int grow = t*128 + row;
  bool v = grow < Rv;
  const float* src = in + (size_t)grow*K;
  size_t pb = (size_t)t*K*128;
  int NKS = K >> 3;
  for (int ks = ksh; ks < NKS; ks += 2){
    float x[8];
    if (v){
      float4 a = *(const float4*)(src + ks*8);
      float4 b = *(const float4*)(src + ks*8 + 4);
      x[0]=a.x;x[1]=a.y;x[2]=a.z;x[3]=a.w;x[4]=b.x;x[5]=b.y;x[6]=b.z;x[7]=b.w;
    } else {
#pragma unroll
      for (int j=0;j<8;j++) x[j]=0.f;
    }
    short8 h;
#pragma unroll
    for (int j=0;j<8;j++) h[j] = (short)bf16rne(x[j]);
    *(short8*)&Ph[pb + (size_t)ks*1024 + row*8] = h;
  }
}

// ---- weight convert: fp32 [K][N] -> tiled bf16 plane over n rows ----
// perm=1: gate-interleave columns (n = gate*256+jj -> pc)
__global__ void btrans_t(const float* __restrict__ in, int K, int N,
                         u16* __restrict__ Ph, int perm){
  __shared__ float t[32][33];
  int k0 = blockIdx.x*32, n0 = blockIdx.y*32;
  int tx = threadIdx.x, ty = threadIdx.y;
  for (int r=0;r<32;r+=8) t[ty+r][tx] = in[(size_t)(k0+ty+r)*N + n0+tx];
  __syncthreads();
  for (int r=0;r<32;r+=8){
    int n = n0+ty+r, k = k0+tx;
    float x = t[tx][ty+r];
    int ne = n;
    if (perm){
      int gate = n>>8, jj = n&255;
      ne = (jj>>5)*128 + ((jj>>4)&1)*64 + (gate<<4) + (jj&15);
    }
    size_t off = (size_t)(ne>>7)*K*128 + (size_t)(k>>3)*1024 + (size_t)(ne&127)*8 + (k&7);
    Ph[off] = bf16rne(x);
  }
}

// ---------------- bf16 MFMA GEMM, global_load_lds, BK=64 ----------------
// FUSED=0: C[M,N] = [A1|A2] @ B (plain store).
// FUSED=1: gate GEMM with gate-permuted B (N=1024); LSTM epilogue, out [M,256].
//   mode 0: out=h ; 1: out=relu(h) ; 2: out=relu((out+h)/2)
//   plane: optional bf16 tiled plane of result (K=256); avgdst=(avgsrc+v)/2.
template<int FUSED>
__global__ __launch_bounds__(256) void gemm_bf(
    const u16* __restrict__ A1, int K1,
    const u16* __restrict__ A2, int K2,
    const u16* __restrict__ Bp,
    float* __restrict__ C, int M, int N,
    const float* __restrict__ bias, const float* __restrict__ c_in,
    u16* __restrict__ plane, const float* __restrict__ avgsrc,
    float* __restrict__ avgdst, int mode)
{
  const int KB = K1 + K2;
  __shared__ u16 SA[8192];
  __shared__ u16 SB[8192];
  const int tid = threadIdx.x;
  const int tm = blockIdx.x, tn = blockIdx.y;
  const int w = tid >> 6, l = tid & 63;
  const int wr = w >> 1, wc = w & 1;
  const int lm = l & 15, lk = l >> 4;

  f32x4 acc[4][4];
#pragma unroll
  for (int i=0;i<4;i++)
#pragma unroll
    for (int j=0;j<4;j++) acc[i][j] = (f32x4){0.f,0.f,0.f,0.f};

  const size_t a1b = (size_t)tm*K1*128, a2b = (size_t)tm*K2*128;
  const size_t bb  = (size_t)tn*KB*128;

  for (int k0 = 0; k0 < KB; k0 += 64) {
    const u16* gA = (k0 < K1) ? A1 + a1b + (size_t)k0*128
                              : A2 + a2b + (size_t)(k0-K1)*128;
    const u16* gB = Bp + bb + (size_t)k0*128;
    const u16* gp; u16* lp;
    if (w < 2){ gp = gA + w*4096; lp = SA + w*4096; }
    else      { gp = gB + (w-2)*4096; lp = SB + (w-2)*4096; }
    const char* g = (const char*)gp + (l<<4);
#pragma unroll
    for (int i=0;i<8;i++) gload16(g + i*1024, lp + i*512);
    __syncthreads();
#pragma unroll
    for (int t=0;t<2;t++){
      short8 ah[4], bh[4];
      const int ko = (t*4 + lk)*1024;
#pragma unroll
      for (int i=0;i<4;i++){
        ah[i] = *(short8*)&SA[ko + (wr*64 + i*16 + lm)*8];
        bh[i] = *(short8*)&SB[ko + (wc*64 + i*16 + lm)*8];
      }
#pragma unroll
      for (int i=0;i<4;i++)
#pragma unroll
        for (int j=0;j<4;j++)
          acc[i][j] = __builtin_amdgcn_mfma_f32_16x16x32_bf16(ah[i], bh[j], acc[i][j], 0,0,0);
    }
    __syncthreads();
  }

  if (FUSED == 0){
    const int bm = tm*128, bn = tn*128;
#pragma unroll
    for (int i=0;i<4;i++){
      int row0 = bm + wr*64 + i*16 + lk*4;
#pragma unroll
      for (int r=0;r<4;r++){
        int row = row0 + r;
        if (row < M){
          float* Cr = C + (size_t)row*N + bn + wc*64 + lm;
#pragma unroll
          for (int j=0;j<4;j++) Cr[j*16] = acc[i][j][r];
        }
      }
    }
  } else {
    // acc[i][j] : j = gate (i,f,g,o) for output column jj
    const int bm = tm*128;
    const int jj = tn*32 + wc*16 + lm;
    const float bi = bias[jj], bf_ = bias[256+jj], bg = bias[512+jj], bo = bias[768+jj];
#pragma unroll
    for (int i=0;i<4;i++){
      int row0 = bm + wr*64 + i*16 + lk*4;
#pragma unroll
      for (int r=0;r<4;r++){
        int row = row0 + r;
        if (row >= M) continue;
        float ig = acc[i][0][r] + bi;
        float fg = acc[i][1][r] + bf_;
        float gg = acc[i][2][r] + bg;
        float og = acc[i][3][r] + bo;
        float cc = c_in[(size_t)row*256 + jj];
        float c2 = fsig(fg)*cc + fsig(ig)*ftanh(gg);
        float h  = fsig(og)*ftanh(c2);
        float* op = C + (size_t)row*256 + jj;
        float v;
        if (mode == 0){ v = h; *op = v; }
        else if (mode == 1){ v = fmaxf(h, 0.f); *op = v; }
        else { float p = *op; v = fmaxf((p+h)*0.5f, 0.f); *op = v; }
        if (mode != 0){
          if (plane)
            plane[(size_t)(row>>7)*32768 + (size_t)(jj>>3)*1024 + (row&127)*8 + (jj&7)] = bf16rne(v);
          if (avgdst)
            avgdst[(size_t)row*256 + jj] = (avgsrc[(size_t)row*256 + jj] + v)*0.5f;
        }
      }
    }
  }
}

// ---------------- attention pooling -> bf16 plane (K=512) ----------------
__global__ __launch_bounds__(256) void att_pool(
    const float* __restrict__ C1, const float* __restrict__ q,
    u16* __restrict__ plane, int ns, int r0)
{
  __shared__ float xh[20*512];
  int b0 = blockIdx.x * 4;
  int nrows = (ns - b0) * 5; if (nrows > 20) nrows = 20; if (nrows < 0) nrows = 0;
  for (int f = threadIdx.x; f < 2560; f += 256) {
    int row = f >> 7, c4 = (f & 127) << 2;
    float4 v = make_float4(0.f,0.f,0.f,0.f);
    if (row < nrows) v = *(const float4*)(C1 + (size_t)(b0*5+row)*512 + c4);
    *(float4*)&xh[row*512 + c4] = v;
  }
  __syncthreads();
  int wid = threadIdx.x >> 6, lane = threadIdx.x & 63;
  int n = b0 + wid;
  if (n >= ns) return;
  const float* X = &xh[wid*5*512];
  float att[4][5];
#pragma unroll
  for (int h=0; h<4; h++) {
#pragma unroll
    for (int s=0; s<5; s++) {
      float d = X[s*512 + h*128 + lane]      * q[h*128 + lane]
              + X[s*512 + h*128 + 64 + lane] * q[h*128 + 64 + lane];
#pragma unroll
      for (int off=32; off; off>>=1) d += __shfl_xor(d, off);
      att[h][s] = d > 0.f ? d : 0.2f*d;
    }
    float m = att[h][0];
#pragma unroll
    for (int s=1;s<5;s++) m = fmaxf(m, att[h][s]);
    float sum = 0.f;
#pragma unroll
    for (int s=0;s<5;s++){ att[h][s] = __expf(att[h][s]-m); sum += att[h][s]; }
    float inv = 1.f/sum;
#pragma unroll
    for (int s=0;s<5;s++) att[h][s] *= inv;
  }
  int c0 = lane * 8;
  int h = c0 >> 7;
  float o[8] = {0,0,0,0,0,0,0,0};
#pragma unroll
  for (int s=0;s<5;s++) {
    float w = att[h][s];
    const float* Xr = X + s*512 + c0;
#pragma unroll
    for (int j=0;j<8;j++) o[j] = fmaf(w, Xr[j], o[j]);
  }
  int gr = r0 + n;
  short8 hv;
#pragma unroll
  for (int j=0;j<8;j++) hv[j] = (short)bf16rne(o[j]);
  *(short8*)&plane[(size_t)(gr>>7)*65536 + (size_t)lane*1024 + (gr&127)*8] = hv;
}

// ---------------- CSR build ----------------
__global__ void fillz(int* __restrict__ p, int n){
  int i = blockIdx.x*256 + threadIdx.x; if (i < n) p[i] = 0;
}
__global__ void hist_k(const int* __restrict__ dst, int* __restrict__ cnt, int E){
  int e = blockIdx.x*256 + threadIdx.x; if (e < E) atomicAdd(&cnt[dst[e]], 1);
}
__global__ void scan_k(int* __restrict__ cnt, int* __restrict__ offs, int n){
  __shared__ int sm[1024];
  int tid = threadIdx.x;
  int running = 0;
  for (int base = 0; base < n; base += 1024) {
    int i = base + tid;
    int v = (i < n) ? cnt[i] : 0;
    sm[tid] = v;
    __syncthreads();
    for (int off=1; off<1024; off<<=1) {
      int add = (tid >= off) ? sm[tid-off] : 0;
      __syncthreads();
      sm[tid] += add;
      __syncthreads();
    }
    int incl = sm[tid];
    int tot  = sm[1023];
    int excl = running + incl - v;
    if (i < n) { offs[i] = excl; cnt[i] = excl; }
    running += tot;
    __syncthreads();
  }
  if (tid == 0) offs[n] = running;
}
__global__ void place_k(const int* __restrict__ src, const int* __restrict__ dst,
                        int* __restrict__ cur, int* __restrict__ srt, int E){
  int e = blockIdx.x*256 + threadIdx.x;
  if (e < E) { int p = atomicAdd(&cur[dst[e]], 1); srt[p] = src[e]; }
}

// ---------------- segment max (empty -> 0); writes fp32 + bf16 plane ----
__global__ __launch_bounds__(256) void seg_max(
    const float* __restrict__ S, const int* __restrict__ offs,
    const int* __restrict__ ssrc, float* __restrict__ agg,
    u16* __restrict__ plane, int Nt)
{
  int t = blockIdx.x*4 + (threadIdx.x >> 6);
  if (t >= Nt) return;
  int lane = threadIdx.x & 63;
  int e0 = offs[t], e1 = offs[t+1];
  float4 m = make_float4(-INFINITY,-INFINITY,-INFINITY,-INFINITY);
  for (int e = e0; e < e1; e++) {
    int s = ssrc[e];
    float4 v = *(const float4*)(S + (size_t)s*256 + lane*4);
    m.x = fmaxf(m.x,v.x); m.y = fmaxf(m.y,v.y); m.z = fmaxf(m.z,v.z); m.w = fmaxf(m.w,v.w);
  }
  if (e1 == e0) m = make_float4(0.f,0.f,0.f,0.f);
  *(float4*)(agg + (size_t)t*256 + lane*4) = m;
  u16* pp = plane + (size_t)(t>>7)*32768 + (size_t)(lane>>1)*1024 + (size_t)(t&127)*8 + (lane&1)*4;
  pp[0]=bf16rne(m.x); pp[1]=bf16rne(m.y); pp[2]=bf16rne(m.z); pp[3]=bf16rne(m.w);
}

// ---------------- misc ----------------
__global__ void avg2(const float* __restrict__ a, const float* __restrict__ b,
                     float* __restrict__ o, int n4){
  int i = blockIdx.x*256 + threadIdx.x;
  if (i < n4) {
    float4 x = ((const float4*)a)[i], y = ((const float4*)b)[i];
    float4 r; r.x=(x.x+y.x)*0.5f; r.y=(x.y+y.y)*0.5f; r.z=(x.z+y.z)*0.5f; r.w=(x.w+y.w)*0.5f;
    ((float4*)o)[i] = r;
  }
}

__global__ __launch_bounds__(256) void matvec(const float* __restrict__ X,
    const float* __restrict__ w, const float* __restrict__ bias,
    float* __restrict__ o, int N){
  int r = blockIdx.x*4 + (threadIdx.x >> 6);
  if (r >= N) return;
  int lane = threadIdx.x & 63;
  float4 x  = *(const float4*)(X + (size_t)r*256 + lane*4);
  float4 ww = *(const float4*)(w + lane*4);
  float d = x.x*ww.x + x.y*ww.y + x.z*ww.z + x.w*ww.w;
#pragma unroll
  for (int off=32; off; off>>=1) d += __shfl_xor(d, off);
  if (lane == 0) o[r] = d + bias[0];
}

// att_W [4,512,128] -> Wcat [512,512] : Wcat[d][h*128+k] = att_W[h][d][k]
__global__ void repack_attw(const float* __restrict__ W, float* __restrict__ o){
  int idx = blockIdx.x*256 + threadIdx.x;
  if (idx >= 4*512*128) return;
  int h = idx >> 16, rem = idx & 65535;
  int d = rem >> 7, k = rem & 127;
  o[(size_t)d*512 + h*128 + k] = W[idx];
}

// Whh [1024,256] -> out [256,1024]
__global__ void transpose_wh(const float* __restrict__ in, float* __restrict__ out){
  __shared__ float t[32][33];
  int rb = blockIdx.x*32, cb = blockIdx.y*32;
  int tx = threadIdx.x, ty = threadIdx.y;
  for (int i=0;i<32;i+=8) t[ty+i][tx] = in[(size_t)(rb+ty+i)*256 + cb+tx];
  __syncthreads();
  for (int i=0;i<32;i+=8) out[(size_t)(cb+ty+i)*1024 + rb+tx] = t[tx][ty+i];
}

// ---------------------------------------------------------------------------
extern "C" void kernel_launch(void* const* d_in, const int* in_sizes, int n_in,
                              void* d_out, int out_size, void* d_ws, size_t ws_size,
                              hipStream_t stream)
{
  const float* x_spot = (const float*)d_in[0];
  const float* x_user = (const float*)d_in[1];
  const float* attW   = (const float*)d_in[2];
  const float* attq   = (const float*)d_in[3];
  const float* Wsrc0[3] = { (const float*)d_in[4], (const float*)d_in[5], (const float*)d_in[6] };
  const float* Wtgt0[3] = { (const float*)d_in[7], (const float*)d_in[8], (const float*)d_in[9] };
  const float* Wih0 = (const float*)d_in[10];
  const float* Whh0 = (const float*)d_in[11];
  const float* b0   = (const float*)d_in[12];
  const float* Wsrc1 = (const float*)d_in[13];
  const float* Wtgt1 = (const float*)d_in[14];
  const float* Wih1 = (const float*)d_in[15];
  const float* Whh1 = (const float*)d_in[16];
  const float* b1   = (const float*)d_in[17];
  const float* linSW = (const float*)d_in[18];
  const float* linSb = (const float*)d_in[19];
  const float* linUW = (const float*)d_in[20];
  const float* linUb = (const float*)d_in[21];
  const int* src_us = (const int*)d_in[22];
  const int* dst_us = (const int*)d_in[23];
  const int* src_su = (const int*)d_in[24];
  const int* dst_su = (const int*)d_in[25];
  const int* src_ss = (const int*)d_in[26];
  const int* dst_ss = (const int*)d_in[27];
  float* out = (float*)d_out;
  float* ws  = (float*)d_ws;
  int*   wsi = (int*)d_ws;

  // ---- fp32 workspace (float offsets) ----
  const size_t SCR   = 0;          // 12.9M (att C1 chunk / src S)
  const size_t AGG0  = 13000000;   // [20000,256]
  const size_t AGG1  = 18200000;   // [40000,256]
  const size_t AGG2  = 28500000;   // [20000,256]
  const size_t METAS = 33700000;   // [20000,256]
  const size_t X1S   = 38900000;
  const size_t X1U   = 44100000;
  const size_t X2S   = 54400000;
  const size_t X2U   = 59600000;
  const size_t BCF   = 69900000;   // [<=1024,1024] B_cat build scratch
  const size_t WCATF = 71000000;   // [512,512]
  const size_t IBASE = 71300000;   // ints
  const int OF_US = 0,      CU_US = 20001,  SR_US = 40001;
  const int OF_SU = 240001, CU_SU = 280002, SR_SU = 320002;
  const int OF_SS = 520002, CU_SS = 540003, SR_SS = 560003;
  int* ib = wsi + IBASE;

  // ---- bf16 tiled planes (u16 offsets from hb) ----
  u16* hb = (u16*)(ws + 72100000);
  const size_t ATT_A = 0;          // 25088x512
  const size_t WCATP = 12845056;   // 512x512
  const size_t WUS0  = 13107200;   // 256x256
  const size_t WSU0  = 13172736;   // 256x512
  const size_t WSS0  = 13303808;   // 256x512
  const size_t WUS1  = 13434880;   // 256x256
  const size_t WSU1  = 13500416;
  const size_t WSS1  = 13565952;
  const size_t BCP_[6] = { 13631488, 14417920, 14942208,   // L0: 768,512,768 x1024
                           15728640, 16252928, 16777216 }; // L1: 512 x1024 x3
  const size_t X0P  = 17301504;    // 20096x512
  const size_t XSP  = 27590656;    // 20096x256 (L1 spot feats)
  const size_t XUP  = 32735232;    // 40064x256 (L0 user feats)
  const size_t XUP2 = 42991616;    // 40064x256 (L1 user feats)
  const size_t A0P  = 53248000;    // 20096x256
  const size_t A1P  = 58392576;    // 40064x256
  const size_t A2P  = 68648960;    // 20096x256

  // ---- phase 0: weight prep ----
  repack_attw<<<1024,256,0,stream>>>(attW, ws+WCATF);
  btrans_t<<<dim3(16,16),dim3(32,8),0,stream>>>(ws+WCATF, 512, 512, hb+WCATP, 0);
  btrans_t<<<dim3(8,8),  dim3(32,8),0,stream>>>(Wsrc0[0], 256, 256, hb+WUS0, 0);
  btrans_t<<<dim3(16,8), dim3(32,8),0,stream>>>(Wsrc0[1], 512, 256, hb+WSU0, 0);
  btrans_t<<<dim3(16,8), dim3(32,8),0,stream>>>(Wsrc0[2], 512, 256, hb+WSS0, 0);
  btrans_t<<<dim3(8,8),  dim3(32,8),0,stream>>>(Wsrc1,        256, 256, hb+WUS1, 0);
  btrans_t<<<dim3(8,8),  dim3(32,8),0,stream>>>(Wsrc1+65536,  256, 256, hb+WSU1, 0);
  btrans_t<<<dim3(8,8),  dim3(32,8),0,stream>>>(Wsrc1+131072, 256, 256, hb+WSS1, 0);

  struct { const float* Wt; int Kt; const float* Wi; const float* Wh; } cfg[6] = {
    { Wtgt0[0], 512, Wih0,        Whh0        },
    { Wtgt0[1], 256, Wih0+262144, Whh0+262144 },
    { Wtgt0[2], 512, Wih0+524288, Whh0+524288 },
    { Wtgt1,        256, Wih1,        Whh1        },
    { Wtgt1+65536,  256, Wih1+262144, Whh1+262144 },
    { Wtgt1+131072, 256, Wih1+524288, Whh1+524288 },
  };
  for (int i=0;i<6;i++){
    int Kt = cfg[i].Kt, KBt = Kt + 256;
    gemm_wt<<<dim3((Kt+127)/128,8),256,0,stream>>>(cfg[i].Wt, 256, cfg[i].Wi, ws+BCF, Kt, 1024);
    transpose_wh<<<dim3(32,8),dim3(32,8),0,stream>>>(cfg[i].Wh, ws+BCF + (size_t)Kt*1024);
    btrans_t<<<dim3(KBt/32,32),dim3(32,8),0,stream>>>(ws+BCF, KBt, 1024, hb+BCP_[i], 1);
  }

  // ---- phase 1: attention -> X0P plane (4 chunks of 5000 spots) ----
  for (int c=0;c<4;c++){
    cvt1<<<196,256,0,stream>>>(x_spot + (size_t)c*12800000, 25000, 512, hb+ATT_A);
    gemm_bf<0><<<dim3(196,4),256,0,stream>>>(hb+ATT_A, 512, hb+ATT_A, 0, hb+WCATP,
        ws+SCR, 25000, 512, nullptr, nullptr, nullptr, nullptr, nullptr, 0);
    att_pool<<<1250,256,0,stream>>>(ws+SCR, attq, hb+X0P, 5000, c*5000);
  }

  // ---- phase 2: CSR ----
  struct { const int* src; const int* dst; int E; int Nt; int of, cu, sr; } et[3] = {
    { src_us, dst_us, 200000, 20000, OF_US, CU_US, SR_US },
    { src_su, dst_su, 200000, 40000, OF_SU, CU_SU, SR_SU },
    { src_ss, dst_ss, 100000, 20000, OF_SS, CU_SS, SR_SS },
  };
  for (int i=0;i<3;i++){
    fillz<<<(et[i].Nt+255)/256,256,0,stream>>>(ib+et[i].cu, et[i].Nt);
    hist_k<<<(et[i].E+255)/256,256,0,stream>>>(et[i].dst, ib+et[i].cu, et[i].E);
    scan_k<<<1,1024,0,stream>>>(ib+et[i].cu, ib+et[i].of, et[i].Nt);
    place_k<<<(et[i].E+255)/256,256,0,stream>>>(et[i].src, et[i].dst,
                                                ib+et[i].cu, ib+et[i].sr, et[i].E);
  }

  // L0 user-feature plane
  cvt1<<<313,256,0,stream>>>(x_user, 40000, 256, hb+XUP);

  // ---- layers ----
  for (int L=0; L<2; L++){
    int Ks = (L==0) ? 512 : 256;
    const u16* XSp = (L==0) ? hb+X0P : hb+XSP;
    const u16* XUp = (L==0) ? hb+XUP : hb+XUP2;
    const u16* Wus = hb + (L?WUS1:WUS0);
    const u16* Wsu = hb + (L?WSU1:WSU0);
    const u16* Wss = hb + (L?WSS1:WSS0);
    const u16* BC0 = hb + BCP_[L?3:0];
    const u16* BC1 = hb + BCP_[L?4:1];
    const u16* BC2 = hb + BCP_[L?5:2];
    const float* bb = (L==0) ? b0 : b1;
    float* outS = (L==0) ? ws+X1S : ws+X2S;
    float* outU = (L==0) ? ws+X1U : ws+X2U;

    // src GEMMs + scatter-max (+agg planes)
    gemm_bf<0><<<dim3(313,2),256,0,stream>>>(XUp, 256, XUp, 0, Wus,
        ws+SCR, 40000, 256, nullptr,nullptr,nullptr,nullptr,nullptr,0);
    seg_max<<<5000,256,0,stream>>>(ws+SCR, ib+OF_US, ib+SR_US, ws+AGG0, hb+A0P, 20000);
    gemm_bf<0><<<dim3(157,2),256,0,stream>>>(XSp, Ks, XSp, 0, Wsu,
        ws+SCR, 20000, 256, nullptr,nullptr,nullptr,nullptr,nullptr,0);
    seg_max<<<10000,256,0,stream>>>(ws+SCR, ib+OF_SU, ib+SR_SU, ws+AGG1, hb+A1P, 40000);
    gemm_bf<0><<<dim3(157,2),256,0,stream>>>(XSp, Ks, XSp, 0, Wss,
        ws+SCR, 20000, 256, nullptr,nullptr,nullptr,nullptr,nullptr,0);
    seg_max<<<5000,256,0,stream>>>(ws+SCR, ib+OF_SS, ib+SR_SS, ws+AGG2, hb+A2P, 20000);
    avg2<<<5000,256,0,stream>>>(ws+AGG0, ws+AGG2, ws+METAS, 1280000);

    // fused gate GEMM + LSTM epilogue
    // e0 -> spot, mode 0 (partial h)
    gemm_bf<1><<<dim3(157,8),256,0,stream>>>(XSp, Ks, hb+A0P, 256, BC0,
        outS, 20000, 1024, bb+0, ws+METAS, nullptr, nullptr, nullptr, 0);
    // e1 -> user, mode 1
    gemm_bf<1><<<dim3(313,8),256,0,stream>>>(XUp, 256, hb+A1P, 256, BC1,
        outU, 40000, 1024, bb+1024, ws+AGG1,
        (L==0) ? hb+XUP2 : nullptr,
        (L==0) ? nullptr : ws+X1U,
        (L==0) ? nullptr : out+5120000, 1);
    // e2 -> spot, mode 2 (final)
    gemm_bf<1><<<dim3(157,8),256,0,stream>>>(XSp, Ks, hb+A2P, 256, BC2,
        outS, 20000, 1024, bb+2048, ws+METAS,
        (L==0) ? hb+XSP : nullptr,
        (L==0) ? nullptr : ws+X1S,
        (L==0) ? nullptr : out, 2);
  }

  // ---- output heads ----
  matvec<<<5000,256,0,stream>>>(ws+X2S, linSW, linSb, out+15360000, 20000);
  matvec<<<10000,256,0,stream>>>(ws+X2U, linUW, linUb, out+15380000, 40000);

  (void)in_sizes; (void)n_in; (void)out_size; (void)ws_size;
}